// Round 1
// baseline (691.691 us; speedup 1.0000x reference)
//
#include <hip/hip_runtime.h>
#include <cmath>

// ---------------------------------------------------------------------------
// DistanceAwareMultiheadAttention  (N=1536, E=49152, D=512, H=8, DH=64)
//
// Round 1: all-f32 correctness baseline.
//   logits[h,q,r] = 2*qk + A(rel) + B(rel);   rel sparse (E of N^2 nonzero)
//   A at rel==0 is row-constant (softmax-invariant -> dropped);
//   B at rel==0 is kodd[r,h] (per-column bias);
//   edge corrections precomputed per (edge, head) into delta[E,H], looked up
//   via dense eid[N,N] int32 map inside a flash-style fused attention kernel.
// ---------------------------------------------------------------------------

constexpr int Nn  = 1536;
constexpr int Dd  = 512;
constexpr int Hh  = 8;
constexpr int DHd = 64;
constexpr float SCALE_F = 362.03867196751236f;   // 256*sqrt(2)

// ---------------------------- QKV projection -------------------------------
// C[n,j] = sum_d feat[n,d] * W[j,d] + b[j]   (q = feat @ W.T + b)
// 64x64 tile, 256 threads, 4x4 micro-tile, BK=16, LDS pad 17 (2-way max).
__global__ __launch_bounds__(256) void qkv_gemm_k(
    const float* __restrict__ feat,
    const float* __restrict__ Wq, const float* __restrict__ bq,
    const float* __restrict__ Wk, const float* __restrict__ bk,
    const float* __restrict__ Wv, const float* __restrict__ bv,
    float* __restrict__ Qo, float* __restrict__ Ko, float* __restrict__ Vo)
{
    const int z = blockIdx.z;
    const float* __restrict__ W    = (z == 0) ? Wq : (z == 1) ? Wk : Wv;
    const float* __restrict__ bias = (z == 0) ? bq : (z == 1) ? bk : bv;
    float* __restrict__ outp       = (z == 0) ? Qo : (z == 1) ? Ko : Vo;

    const int row0 = blockIdx.y * 64;
    const int col0 = blockIdx.x * 64;
    __shared__ float As[64][17];
    __shared__ float Bs[64][17];
    const int tid = threadIdx.x;
    const int tx = tid & 15, ty = tid >> 4;
    const int lr = tid >> 2;            // 0..63 staging row
    const int lc = (tid & 3) << 2;      // 0,4,8,12 staging col
    float acc[4][4] = {{0.f, 0.f, 0.f, 0.f}};

    for (int k0 = 0; k0 < Dd; k0 += 16) {
        __syncthreads();
        float4 a4 = *(const float4*)(feat + (size_t)(row0 + lr) * Dd + k0 + lc);
        float4 b4 = *(const float4*)(W    + (size_t)(col0 + lr) * Dd + k0 + lc);
        As[lr][lc + 0] = a4.x; As[lr][lc + 1] = a4.y; As[lr][lc + 2] = a4.z; As[lr][lc + 3] = a4.w;
        Bs[lr][lc + 0] = b4.x; Bs[lr][lc + 1] = b4.y; Bs[lr][lc + 2] = b4.z; Bs[lr][lc + 3] = b4.w;
        __syncthreads();
        #pragma unroll
        for (int kk = 0; kk < 16; ++kk) {
            float av[4], bv4[4];
            #pragma unroll
            for (int i = 0; i < 4; ++i) av[i]  = As[ty * 4 + i][kk];
            #pragma unroll
            for (int j = 0; j < 4; ++j) bv4[j] = Bs[tx * 4 + j][kk];
            #pragma unroll
            for (int i = 0; i < 4; ++i) {
                #pragma unroll
                for (int j = 0; j < 4; ++j) acc[i][j] = fmaf(av[i], bv4[j], acc[i][j]);
            }
        }
    }
    #pragma unroll
    for (int i = 0; i < 4; ++i) {
        float4 o;
        o.x = acc[i][0] + bias[col0 + tx * 4 + 0];
        o.y = acc[i][1] + bias[col0 + tx * 4 + 1];
        o.z = acc[i][2] + bias[col0 + tx * 4 + 2];
        o.w = acc[i][3] + bias[col0 + tx * 4 + 3];
        *(float4*)(outp + (size_t)(row0 + ty * 4 + i) * Dd + col0 + tx * 4) = o;
    }
}

// ------------------------- rel / eid init + scatter -------------------------
__global__ void init_rel_k(float* __restrict__ rel, int* __restrict__ eid)
{
    size_t i = (size_t)blockIdx.x * 256 + threadIdx.x;
    if (i < (size_t)Nn * Nn) { rel[i] = 0.f; eid[i] = -1; }
}

// edge_index dtype hedge: detect int64 (high words all zero) vs int32.
__global__ void norm_idx_k(const int* __restrict__ raw, int* __restrict__ idxn, int E2)
{
    int e = blockIdx.x * 256 + threadIdx.x;
    if (e >= E2) return;
    int acc = 0;
    #pragma unroll
    for (int i = 0; i < 16; ++i) acc |= raw[2 * i + 1];
    int v;
    if (acc == 0) v = raw[2 * e];   // int64 little-endian: low words at even offsets
    else          v = raw[e];       // plain int32
    idxn[e] = v;
}

__global__ void scatter_k(const int* __restrict__ idxn, const float* __restrict__ attr,
                          float* __restrict__ rel, int* __restrict__ eid, int E)
{
    int e = blockIdx.x * 256 + threadIdx.x;
    if (e >= E) return;
    int s = idxn[e], t = idxn[E + e];
    size_t off = (size_t)s * Nn + t;
    atomicAdd(rel + off, attr[e] * SCALE_F);
    eid[off] = e;   // duplicate edges: either id is fine (delta from summed rel)
}

// ------------------ odd-index sums (PE at rel==0 constants) -----------------
__global__ void oddsum_k(const float* __restrict__ Q, const float* __restrict__ K,
                         float* __restrict__ qodd, float* __restrict__ kodd)
{
    int t = blockIdx.x * 256 + threadIdx.x;
    if (t >= 2 * Nn * Hh) return;
    const float* src = (t < Nn * Hh) ? Q : K;
    float* dst       = (t < Nn * Hh) ? qodd : kodd;
    int i = (t < Nn * Hh) ? t : t - Nn * Hh;
    int n = i >> 3, h = i & 7;
    const float* row = src + (size_t)n * Dd + h * DHd;
    float s = 0.f;
    #pragma unroll
    for (int ii = 0; ii < 32; ++ii) s += row[2 * ii + 1];
    dst[i] = s;
}

// ------------------- per-edge, per-head logit corrections -------------------
// delta[e,h] = sum_i (q_{2i}+k_{2i})*sin(x*div_i) + (q_{2i+1}+k_{2i+1})*cos(x*div_i)
//              - qodd[q,h] - kodd[r,h],   x = rel (already SCALEd, summed)
__global__ void delta_k(const int* __restrict__ idxn, const float* __restrict__ rel,
                        const float* __restrict__ Q, const float* __restrict__ K,
                        const float* __restrict__ qodd, const float* __restrict__ kodd,
                        float* __restrict__ delta, int E)
{
    int e = blockIdx.x * 256 + threadIdx.x;
    if (e >= E) return;
    int qi = idxn[e], ri = idxn[E + e];
    float x = rel[(size_t)qi * Nn + ri];
    float sv[32], cv[32];
    #pragma unroll
    for (int i = 0; i < 32; ++i) {
        float div = expf(-0.28782313662425572f * (float)i);  // 10000^(-i/32)
        sincosf(x * div, &sv[i], &cv[i]);                    // accurate range reduction
    }
    const float* qrow = Q + (size_t)qi * Dd;
    const float* krow = K + (size_t)ri * Dd;
    for (int h = 0; h < Hh; ++h) {
        float acc = 0.f;
        #pragma unroll
        for (int i = 0; i < 32; ++i) {
            float2 q2 = *(const float2*)(qrow + h * DHd + 2 * i);
            float2 k2 = *(const float2*)(krow + h * DHd + 2 * i);
            acc += (q2.x + k2.x) * sv[i] + (q2.y + k2.y) * cv[i];
        }
        delta[(size_t)e * Hh + h] = acc - qodd[qi * Hh + h] - kodd[ri * Hh + h];
    }
}

// --------------------------- fused flash attention --------------------------
// Per (head, 16-q-row tile): iterate 64-wide r tiles; online softmax.
// logit' = 0.25*qk + 0.125*(kodd[r,h] + delta[eid[q,r],h])   (qodd dropped)
// Block 128 = 2 waves; thread = (ty 0..7 -> 2 q-rows, tx 0..15 -> 4 cols).
__global__ __launch_bounds__(128) void flash_k(
    const float* __restrict__ Q, const float* __restrict__ K, const float* __restrict__ V,
    const int* __restrict__ eid, const float* __restrict__ delta,
    const float* __restrict__ kodd, float* __restrict__ outbuf)
{
    const int h  = blockIdx.y;
    const int q0 = blockIdx.x * 16;
    const int tid = threadIdx.x;
    const int tx = tid & 15;
    const int ty = tid >> 4;          // 0..7
    __shared__ float Qs[16][65];
    __shared__ float Ks[64][65];
    __shared__ float Vs[64][65];
    __shared__ float Ps[16][65];
    __shared__ float kos[64];

    for (int i = tid; i < 16 * 16; i += 128) {
        int r = i >> 4, dc = (i & 15) << 2;
        float4 q4 = *(const float4*)(Q + (size_t)(q0 + r) * Dd + h * DHd + dc);
        Qs[r][dc + 0] = q4.x; Qs[r][dc + 1] = q4.y; Qs[r][dc + 2] = q4.z; Qs[r][dc + 3] = q4.w;
    }

    const int ra = 2 * ty, rb = 2 * ty + 1;
    float m0 = -3.0e38f, m1 = -3.0e38f, l0 = 0.f, l1 = 0.f;
    float O0[4] = {0.f, 0.f, 0.f, 0.f}, O1[4] = {0.f, 0.f, 0.f, 0.f};

    for (int r0 = 0; r0 < Nn; r0 += 64) {
        __syncthreads();
        for (int i = tid; i < 64 * 16; i += 128) {
            int r = i >> 4, dc = (i & 15) << 2;
            float4 k4 = *(const float4*)(K + (size_t)(r0 + r) * Dd + h * DHd + dc);
            float4 v4 = *(const float4*)(V + (size_t)(r0 + r) * Dd + h * DHd + dc);
            Ks[r][dc + 0] = k4.x; Ks[r][dc + 1] = k4.y; Ks[r][dc + 2] = k4.z; Ks[r][dc + 3] = k4.w;
            Vs[r][dc + 0] = v4.x; Vs[r][dc + 1] = v4.y; Vs[r][dc + 2] = v4.z; Vs[r][dc + 3] = v4.w;
        }
        if (tid < 64) kos[tid] = kodd[(size_t)(r0 + tid) * Hh + h];
        __syncthreads();

        float s0[4] = {0.f, 0.f, 0.f, 0.f}, s1[4] = {0.f, 0.f, 0.f, 0.f};
        #pragma unroll 16
        for (int kk = 0; kk < 64; ++kk) {
            float a0 = Qs[ra][kk];
            float a1 = Qs[rb][kk];
            #pragma unroll
            for (int j = 0; j < 4; ++j) {
                float b = Ks[tx * 4 + j][kk];
                s0[j] = fmaf(a0, b, s0[j]);
                s1[j] = fmaf(a1, b, s1[j]);
            }
        }

        int4 e0 = *(const int4*)(eid + (size_t)(q0 + ra) * Nn + r0 + tx * 4);
        int4 e1 = *(const int4*)(eid + (size_t)(q0 + rb) * Nn + r0 + tx * 4);
        const int ee0[4] = {e0.x, e0.y, e0.z, e0.w};
        const int ee1[4] = {e1.x, e1.y, e1.z, e1.w};
        float lg0[4], lg1[4];
        #pragma unroll
        for (int j = 0; j < 4; ++j) {
            float kv = kos[tx * 4 + j];
            lg0[j] = 0.25f * s0[j] + 0.125f * kv;
            lg1[j] = 0.25f * s1[j] + 0.125f * kv;
        }
        #pragma unroll
        for (int j = 0; j < 4; ++j) {
            if (ee0[j] >= 0) lg0[j] += 0.125f * delta[(size_t)ee0[j] * Hh + h];
            if (ee1[j] >= 0) lg1[j] += 0.125f * delta[(size_t)ee1[j] * Hh + h];
        }

        float mx0 = fmaxf(fmaxf(lg0[0], lg0[1]), fmaxf(lg0[2], lg0[3]));
        float mx1 = fmaxf(fmaxf(lg1[0], lg1[1]), fmaxf(lg1[2], lg1[3]));
        #pragma unroll
        for (int o = 1; o < 16; o <<= 1) {
            mx0 = fmaxf(mx0, __shfl_xor(mx0, o, 64));
            mx1 = fmaxf(mx1, __shfl_xor(mx1, o, 64));
        }
        float mn0 = fmaxf(m0, mx0), mn1 = fmaxf(m1, mx1);
        float al0 = __expf(m0 - mn0), al1 = __expf(m1 - mn1);
        float p0[4], p1[4];
        #pragma unroll
        for (int j = 0; j < 4; ++j) {
            p0[j] = __expf(lg0[j] - mn0);
            p1[j] = __expf(lg1[j] - mn1);
        }
        float sp0 = (p0[0] + p0[1]) + (p0[2] + p0[3]);
        float sp1 = (p1[0] + p1[1]) + (p1[2] + p1[3]);
        #pragma unroll
        for (int o = 1; o < 16; o <<= 1) {
            sp0 += __shfl_xor(sp0, o, 64);
            sp1 += __shfl_xor(sp1, o, 64);
        }
        l0 = l0 * al0 + sp0;
        l1 = l1 * al1 + sp1;
        m0 = mn0; m1 = mn1;
        #pragma unroll
        for (int j = 0; j < 4; ++j) { O0[j] *= al0; O1[j] *= al1; }
        #pragma unroll
        for (int j = 0; j < 4; ++j) {
            Ps[ra][tx * 4 + j] = p0[j];
            Ps[rb][tx * 4 + j] = p1[j];
        }
        __syncthreads();
        #pragma unroll 16
        for (int rr = 0; rr < 64; ++rr) {
            float a0 = Ps[ra][rr];
            float a1 = Ps[rb][rr];
            #pragma unroll
            for (int j = 0; j < 4; ++j) {
                float b = Vs[rr][tx * 4 + j];
                O0[j] = fmaf(a0, b, O0[j]);
                O1[j] = fmaf(a1, b, O1[j]);
            }
        }
    }

    float inv0 = 1.0f / l0, inv1 = 1.0f / l1;
    float4 oa, ob;
    oa.x = O0[0] * inv0; oa.y = O0[1] * inv0; oa.z = O0[2] * inv0; oa.w = O0[3] * inv0;
    ob.x = O1[0] * inv1; ob.y = O1[1] * inv1; ob.z = O1[2] * inv1; ob.w = O1[3] * inv1;
    *(float4*)(outbuf + (size_t)(q0 + ra) * Dd + h * DHd + tx * 4) = oa;
    *(float4*)(outbuf + (size_t)(q0 + rb) * Dd + h * DHd + tx * 4) = ob;
}

// ------------------------------ max pool -----------------------------------
__global__ void maxpool_k(const float* __restrict__ outbuf, float* __restrict__ outp)
{
    int c = blockIdx.x * 256 + threadIdx.x;
    if (c >= Dd) return;
    float mx = -3.0e38f;
    for (int n = 0; n < Nn; ++n) mx = fmaxf(mx, outbuf[(size_t)n * Dd + c]);
    outp[c] = mx;
}

// ---------------------------------------------------------------------------
extern "C" void kernel_launch(void* const* d_in, const int* in_sizes, int n_in,
                              void* d_out, int out_size, void* d_ws, size_t ws_size,
                              hipStream_t stream)
{
    const float* feat   = (const float*)d_in[0];
    const int*   rawidx = (const int*)d_in[1];
    const float* attr   = (const float*)d_in[2];
    // d_in[3] pos: unused by forward
    const float* Wq = (const float*)d_in[4];
    const float* bq = (const float*)d_in[5];
    const float* Wk = (const float*)d_in[6];
    const float* bk = (const float*)d_in[7];
    const float* Wv = (const float*)d_in[8];
    const float* bv = (const float*)d_in[9];
    float* outp = (float*)d_out;
    const int E = in_sizes[2];

    // workspace layout (floats); outbuf aliases rel (rel dead after delta_k)
    const size_t ND_ = (size_t)Nn * Dd;    // 786432
    const size_t NN_ = (size_t)Nn * Nn;    // 2359296
    float* ws    = (float*)d_ws;
    float* Q     = ws;
    float* K     = Q + ND_;
    float* V     = K + ND_;
    float* rel   = V + ND_;
    int*   eid   = (int*)(rel + NN_);
    float* delta = (float*)(eid + NN_);
    float* qodd  = delta + (size_t)E * Hh;
    float* kodd  = qodd + (size_t)Nn * Hh;
    int*   idxn  = (int*)(kodd + (size_t)Nn * Hh);
    float* outbuf = rel;

    qkv_gemm_k<<<dim3(Dd / 64, Nn / 64, 3), 256, 0, stream>>>(feat, Wq, bq, Wk, bk, Wv, bv, Q, K, V);
    init_rel_k<<<(int)((NN_ + 255) / 256), 256, 0, stream>>>(rel, eid);
    norm_idx_k<<<(2 * E + 255) / 256, 256, 0, stream>>>(rawidx, idxn, 2 * E);
    scatter_k<<<(E + 255) / 256, 256, 0, stream>>>(idxn, attr, rel, eid, E);
    oddsum_k<<<(2 * Nn * Hh + 255) / 256, 256, 0, stream>>>(Q, K, qodd, kodd);
    delta_k<<<(E + 255) / 256, 256, 0, stream>>>(idxn, rel, Q, K, qodd, kodd, delta, E);
    flash_k<<<dim3(Nn / 16, Hh), 128, 0, stream>>>(Q, K, V, eid, delta, kodd, outbuf);
    maxpool_k<<<(Dd + 255) / 256, 256, 0, stream>>>(outbuf, outp);
}

// Round 2
// 500.036 us; speedup vs baseline: 1.3833x; 1.3833x over previous
//
#include <hip/hip_runtime.h>
#include <cmath>

// ---------------------------------------------------------------------------
// DistanceAwareMultiheadAttention  (N=1536, E=49152, D=512, H=8, DH=64)
//
// Round 2: f32 path, LDS-vectorized.
//  - flash_k: 1 wave/block (no barriers), 4x4 micro-tile, all LDS reads are
//    ds_read_b128 over 4 consecutive k elements (row-major, pad 68).
//  - qkv_gemm: BK=32, same b128 4-kk inner product.
//  - maxpool: 2-stage coalesced reduction (was 237us latency-bound).
// ---------------------------------------------------------------------------

constexpr int Nn  = 1536;
constexpr int Dd  = 512;
constexpr int Hh  = 8;
constexpr int DHd = 64;
constexpr float SCALE_F = 362.03867196751236f;   // 256*sqrt(2)

typedef float f4 __attribute__((ext_vector_type(4)));
typedef int   i4 __attribute__((ext_vector_type(4)));

// ---------------------------- QKV projection -------------------------------
// C[n,j] = sum_d feat[n,d] * W[j,d] + b[j]. 64x64 tile, 256 thr, 4x4 micro,
// BK=32, row-major LDS pad 36, b128 reads over 4-kk chunks.
__global__ __launch_bounds__(256) void qkv_gemm_k(
    const float* __restrict__ feat,
    const float* __restrict__ Wq, const float* __restrict__ bq,
    const float* __restrict__ Wk, const float* __restrict__ bk,
    const float* __restrict__ Wv, const float* __restrict__ bv,
    float* __restrict__ Qo, float* __restrict__ Ko, float* __restrict__ Vo)
{
    const int z = blockIdx.z;
    const float* __restrict__ W    = (z == 0) ? Wq : (z == 1) ? Wk : Wv;
    const float* __restrict__ bias = (z == 0) ? bq : (z == 1) ? bk : bv;
    float* __restrict__ outp       = (z == 0) ? Qo : (z == 1) ? Ko : Vo;

    const int row0 = blockIdx.y * 64;
    const int col0 = blockIdx.x * 64;
    __shared__ float As[64][36];
    __shared__ float Bs[64][36];
    const int tid = threadIdx.x;
    const int tx = tid & 15, ty = tid >> 4;
    float acc[4][4] = {{0.f, 0.f, 0.f, 0.f}};

    for (int k0 = 0; k0 < Dd; k0 += 32) {
        __syncthreads();
        #pragma unroll
        for (int it = 0; it < 2; ++it) {
            int i = tid + it * 256;
            int r = i >> 3, kc = (i & 7) << 2;
            f4 a = *(const f4*)(feat + (size_t)(row0 + r) * Dd + k0 + kc);
            f4 b = *(const f4*)(W    + (size_t)(col0 + r) * Dd + k0 + kc);
            *(f4*)&As[r][kc] = a;
            *(f4*)&Bs[r][kc] = b;
        }
        __syncthreads();
        #pragma unroll
        for (int kk = 0; kk < 32; kk += 4) {
            f4 av[4], bv4[4];
            #pragma unroll
            for (int i = 0; i < 4; ++i) av[i]  = *(const f4*)&As[4 * ty + i][kk];
            #pragma unroll
            for (int j = 0; j < 4; ++j) bv4[j] = *(const f4*)&Bs[4 * tx + j][kk];
            #pragma unroll
            for (int i = 0; i < 4; ++i)
                #pragma unroll
                for (int j = 0; j < 4; ++j)
                    #pragma unroll
                    for (int c = 0; c < 4; ++c)
                        acc[i][j] = fmaf(av[i][c], bv4[j][c], acc[i][j]);
        }
    }
    #pragma unroll
    for (int i = 0; i < 4; ++i) {
        f4 o;
        #pragma unroll
        for (int j = 0; j < 4; ++j) o[j] = acc[i][j] + bias[col0 + tx * 4 + j];
        *(f4*)(outp + (size_t)(row0 + ty * 4 + i) * Dd + col0 + tx * 4) = o;
    }
}

// ------------------------- rel / eid init + scatter -------------------------
__global__ void init_rel_k(float* __restrict__ rel, int* __restrict__ eid)
{
    size_t i = (size_t)blockIdx.x * 256 + threadIdx.x;
    if (i < (size_t)Nn * Nn) { rel[i] = 0.f; eid[i] = -1; }
}

// edge_index dtype hedge: detect int64 (high words all zero) vs int32.
__global__ void norm_idx_k(const int* __restrict__ raw, int* __restrict__ idxn, int E2)
{
    int e = blockIdx.x * 256 + threadIdx.x;
    if (e >= E2) return;
    int acc = 0;
    #pragma unroll
    for (int i = 0; i < 16; ++i) acc |= raw[2 * i + 1];
    int v;
    if (acc == 0) v = raw[2 * e];
    else          v = raw[e];
    idxn[e] = v;
}

__global__ void scatter_k(const int* __restrict__ idxn, const float* __restrict__ attr,
                          float* __restrict__ rel, int* __restrict__ eid, int E)
{
    int e = blockIdx.x * 256 + threadIdx.x;
    if (e >= E) return;
    int s = idxn[e], t = idxn[E + e];
    size_t off = (size_t)s * Nn + t;
    atomicAdd(rel + off, attr[e] * SCALE_F);
    eid[off] = e;
}

// ------------------ odd-index sums (PE at rel==0 constants) -----------------
__global__ void oddsum_k(const float* __restrict__ Q, const float* __restrict__ K,
                         float* __restrict__ qodd, float* __restrict__ kodd)
{
    int t = blockIdx.x * 256 + threadIdx.x;
    if (t >= 2 * Nn * Hh) return;
    const float* src = (t < Nn * Hh) ? Q : K;
    float* dst       = (t < Nn * Hh) ? qodd : kodd;
    int i = (t < Nn * Hh) ? t : t - Nn * Hh;
    int n = i >> 3, h = i & 7;
    const float* row = src + (size_t)n * Dd + h * DHd;
    float s = 0.f;
    #pragma unroll
    for (int ii = 0; ii < 32; ++ii) s += row[2 * ii + 1];
    dst[i] = s;
}

// ------------------- per-edge, per-head logit corrections -------------------
__global__ void delta_k(const int* __restrict__ idxn, const float* __restrict__ rel,
                        const float* __restrict__ Q, const float* __restrict__ K,
                        const float* __restrict__ qodd, const float* __restrict__ kodd,
                        float* __restrict__ delta, int E)
{
    int e = blockIdx.x * 256 + threadIdx.x;
    if (e >= E) return;
    int qi = idxn[e], ri = idxn[E + e];
    float x = rel[(size_t)qi * Nn + ri];
    float sv[32], cv[32];
    #pragma unroll
    for (int i = 0; i < 32; ++i) {
        float div = expf(-0.28782313662425572f * (float)i);
        sincosf(x * div, &sv[i], &cv[i]);
    }
    const float* qrow = Q + (size_t)qi * Dd;
    const float* krow = K + (size_t)ri * Dd;
    for (int h = 0; h < Hh; ++h) {
        float acc = 0.f;
        #pragma unroll
        for (int i = 0; i < 32; ++i) {
            float2 q2 = *(const float2*)(qrow + h * DHd + 2 * i);
            float2 k2 = *(const float2*)(krow + h * DHd + 2 * i);
            acc += (q2.x + k2.x) * sv[i] + (q2.y + k2.y) * cv[i];
        }
        delta[(size_t)e * Hh + h] = acc - qodd[qi * Hh + h] - kodd[ri * Hh + h];
    }
}

// --------------------------- fused flash attention --------------------------
// 1 wave per block (64 threads) -> no __syncthreads at all (in-order DS pipe).
// Thread (ty 0..3, tx 0..15): rows 4ty..4ty+3, cols 4tx..4tx+3. All LDS reads
// are b128 over 4 consecutive k/r elements; rows padded to 68 floats.
__global__ __launch_bounds__(64) void flash_k(
    const float* __restrict__ Q, const float* __restrict__ K, const float* __restrict__ V,
    const int* __restrict__ eid, const float* __restrict__ delta,
    const float* __restrict__ kodd, float* __restrict__ outbuf)
{
    const int h  = blockIdx.y;
    const int q0 = blockIdx.x * 16;
    const int tid = threadIdx.x;
    const int tx = tid & 15;
    const int ty = tid >> 4;          // 0..3
    __shared__ float Qs[16][68];
    __shared__ float Ks[64][68];
    __shared__ float Vs[64][68];
    __shared__ float Ps[16][68];

    #pragma unroll
    for (int it = 0; it < 4; ++it) {
        int i = tid + it * 64;
        int r = i >> 4, dc = (i & 15) << 2;
        f4 q4 = *(const f4*)(Q + (size_t)(q0 + r) * Dd + h * DHd + dc);
        *(f4*)&Qs[r][dc] = q4;
    }

    float m_[4], l_[4];
    float O_[4][4];
    #pragma unroll
    for (int i = 0; i < 4; ++i) {
        m_[i] = -3.0e38f; l_[i] = 0.f;
        #pragma unroll
        for (int j = 0; j < 4; ++j) O_[i][j] = 0.f;
    }

    for (int r0 = 0; r0 < Nn; r0 += 64) {
        // stage K,V tiles (coalesced f4; single wave -> DS in-order, no barrier)
        #pragma unroll
        for (int it = 0; it < 16; ++it) {
            int i = tid + it * 64;
            int r = i >> 4, dc = (i & 15) << 2;
            f4 k4 = *(const f4*)(K + (size_t)(r0 + r) * Dd + h * DHd + dc);
            f4 v4 = *(const f4*)(V + (size_t)(r0 + r) * Dd + h * DHd + dc);
            *(f4*)&Ks[r][dc] = k4;
            *(f4*)&Vs[r][dc] = v4;
        }

        // S = Q K^T  (4x4 per thread, b128 feeds)
        float s[4][4] = {{0.f,0.f,0.f,0.f},{0.f,0.f,0.f,0.f},{0.f,0.f,0.f,0.f},{0.f,0.f,0.f,0.f}};
        #pragma unroll 8
        for (int kk = 0; kk < 64; kk += 4) {
            f4 qv[4], kv[4];
            #pragma unroll
            for (int i = 0; i < 4; ++i) qv[i] = *(const f4*)&Qs[4 * ty + i][kk];
            #pragma unroll
            for (int j = 0; j < 4; ++j) kv[j] = *(const f4*)&Ks[4 * tx + j][kk];
            #pragma unroll
            for (int i = 0; i < 4; ++i)
                #pragma unroll
                for (int j = 0; j < 4; ++j)
                    #pragma unroll
                    for (int c = 0; c < 4; ++c)
                        s[i][j] = fmaf(qv[i][c], kv[j][c], s[i][j]);
        }

        // logits = 0.25*s + 0.125*(kodd + delta)
        float kv_[4];
        #pragma unroll
        for (int j = 0; j < 4; ++j) kv_[j] = kodd[(size_t)(r0 + 4 * tx + j) * Hh + h];
        float lg[4][4];
        #pragma unroll
        for (int i = 0; i < 4; ++i) {
            i4 e = *(const i4*)(eid + (size_t)(q0 + 4 * ty + i) * Nn + r0 + 4 * tx);
            #pragma unroll
            for (int j = 0; j < 4; ++j) {
                lg[i][j] = 0.25f * s[i][j] + 0.125f * kv_[j];
                if (e[j] >= 0) lg[i][j] += 0.125f * delta[(size_t)e[j] * Hh + h];
            }
        }

        // online softmax per row (reduce over 16 tx lanes)
        #pragma unroll
        for (int i = 0; i < 4; ++i) {
            float mx = fmaxf(fmaxf(lg[i][0], lg[i][1]), fmaxf(lg[i][2], lg[i][3]));
            #pragma unroll
            for (int o = 1; o < 16; o <<= 1) mx = fmaxf(mx, __shfl_xor(mx, o));
            float mn = fmaxf(m_[i], mx);
            float al = __expf(m_[i] - mn);
            f4 p;
            #pragma unroll
            for (int j = 0; j < 4; ++j) p[j] = __expf(lg[i][j] - mn);
            float sp = (p[0] + p[1]) + (p[2] + p[3]);
            #pragma unroll
            for (int o = 1; o < 16; o <<= 1) sp += __shfl_xor(sp, o);
            l_[i] = l_[i] * al + sp;
            m_[i] = mn;
            #pragma unroll
            for (int j = 0; j < 4; ++j) O_[i][j] *= al;
            *(f4*)&Ps[4 * ty + i][4 * tx] = p;
        }

        // O += P V  (b128 feeds)
        #pragma unroll 8
        for (int rr = 0; rr < 64; rr += 4) {
            f4 pv[4];
            #pragma unroll
            for (int i = 0; i < 4; ++i) pv[i] = *(const f4*)&Ps[4 * ty + i][rr];
            #pragma unroll
            for (int t = 0; t < 4; ++t) {
                f4 vv = *(const f4*)&Vs[rr + t][4 * tx];
                #pragma unroll
                for (int i = 0; i < 4; ++i)
                    #pragma unroll
                    for (int j = 0; j < 4; ++j)
                        O_[i][j] = fmaf(pv[i][t], vv[j], O_[i][j]);
            }
        }
    }

    #pragma unroll
    for (int i = 0; i < 4; ++i) {
        float inv = 1.0f / l_[i];
        f4 o;
        #pragma unroll
        for (int j = 0; j < 4; ++j) o[j] = O_[i][j] * inv;
        *(f4*)(outbuf + (size_t)(q0 + 4 * ty + i) * Dd + h * DHd + 4 * tx) = o;
    }
}

// ------------------------------ max pool (2-stage) --------------------------
__global__ __launch_bounds__(128) void mp1_k(const float* __restrict__ outbuf,
                                             float* __restrict__ partial)
{
    const int b = blockIdx.x;        // 24 blocks x 64 rows
    const int t = threadIdx.x;       // 128 thr x 4 cols
    f4 mx = {-3.0e38f, -3.0e38f, -3.0e38f, -3.0e38f};
    for (int r = 0; r < 64; ++r) {
        f4 v = *(const f4*)(outbuf + (size_t)(64 * b + r) * Dd + 4 * t);
        #pragma unroll
        for (int c = 0; c < 4; ++c) mx[c] = fmaxf(mx[c], v[c]);
    }
    *(f4*)(partial + (size_t)b * Dd + 4 * t) = mx;
}

__global__ __launch_bounds__(128) void mp2_k(const float* __restrict__ partial,
                                             float* __restrict__ outp)
{
    const int t = threadIdx.x;
    f4 mx = {-3.0e38f, -3.0e38f, -3.0e38f, -3.0e38f};
    for (int b = 0; b < 24; ++b) {
        f4 v = *(const f4*)(partial + (size_t)b * Dd + 4 * t);
        #pragma unroll
        for (int c = 0; c < 4; ++c) mx[c] = fmaxf(mx[c], v[c]);
    }
    *(f4*)(outp + 4 * t) = mx;
}

// ---------------------------------------------------------------------------
extern "C" void kernel_launch(void* const* d_in, const int* in_sizes, int n_in,
                              void* d_out, int out_size, void* d_ws, size_t ws_size,
                              hipStream_t stream)
{
    const float* feat   = (const float*)d_in[0];
    const int*   rawidx = (const int*)d_in[1];
    const float* attr   = (const float*)d_in[2];
    const float* Wq = (const float*)d_in[4];
    const float* bq = (const float*)d_in[5];
    const float* Wk = (const float*)d_in[6];
    const float* bk = (const float*)d_in[7];
    const float* Wv = (const float*)d_in[8];
    const float* bv = (const float*)d_in[9];
    float* outp = (float*)d_out;
    const int E = in_sizes[2];

    const size_t ND_ = (size_t)Nn * Dd;
    const size_t NN_ = (size_t)Nn * Nn;
    float* ws    = (float*)d_ws;
    float* Q     = ws;
    float* K     = Q + ND_;
    float* V     = K + ND_;
    float* rel   = V + ND_;
    int*   eid   = (int*)(rel + NN_);
    float* delta = (float*)(eid + NN_);
    float* qodd  = delta + (size_t)E * Hh;
    float* kodd  = qodd + (size_t)Nn * Hh;
    int*   idxn  = (int*)(kodd + (size_t)Nn * Hh);
    float* partial = (float*)(idxn + 2 * E);
    float* outbuf = rel;   // rel dead after delta_k

    qkv_gemm_k<<<dim3(Dd / 64, Nn / 64, 3), 256, 0, stream>>>(feat, Wq, bq, Wk, bk, Wv, bv, Q, K, V);
    init_rel_k<<<(int)((NN_ + 255) / 256), 256, 0, stream>>>(rel, eid);
    norm_idx_k<<<(2 * E + 255) / 256, 256, 0, stream>>>(rawidx, idxn, 2 * E);
    scatter_k<<<(E + 255) / 256, 256, 0, stream>>>(idxn, attr, rel, eid, E);
    oddsum_k<<<(2 * Nn * Hh + 255) / 256, 256, 0, stream>>>(Q, K, qodd, kodd);
    delta_k<<<(E + 255) / 256, 256, 0, stream>>>(idxn, rel, Q, K, qodd, kodd, delta, E);
    flash_k<<<dim3(Nn / 16, Hh), 64, 0, stream>>>(Q, K, V, eid, delta, kodd, outbuf);
    mp1_k<<<24, 128, 0, stream>>>(outbuf, partial);
    mp2_k<<<1, 128, 0, stream>>>(partial, outp);
}

// Round 3
// 389.555 us; speedup vs baseline: 1.7756x; 1.2836x over previous
//
#include <hip/hip_runtime.h>
#include <cmath>

// ---------------------------------------------------------------------------
// DistanceAwareMultiheadAttention  (N=1536, E=49152, D=512, H=8, DH=64)
//
// Round 3: flash attention -> split-bf16 MFMA (16x16x32), fragment-packed
// Q/K/V in global memory, 1-wave blocks, split-K(2) + combine.
// qkv_gemm / scatter / delta unchanged (f32) this round.
// ---------------------------------------------------------------------------

constexpr int Nn  = 1536;
constexpr int Dd  = 512;
constexpr int Hh  = 8;
constexpr int DHd = 64;
constexpr float SCALE_F = 362.03867196751236f;   // 256*sqrt(2)

typedef float f4 __attribute__((ext_vector_type(4)));
typedef int   i4 __attribute__((ext_vector_type(4)));
typedef __attribute__((ext_vector_type(4))) float f32x4;
typedef __attribute__((ext_vector_type(8))) short bf16x8;

__device__ inline unsigned short bf16_rne(float x) {
    unsigned u = __float_as_uint(x);
    unsigned r = u + 0x7fff + ((u >> 16) & 1);
    return (unsigned short)(r >> 16);
}
__device__ inline float bf16_tof(unsigned short h) {
    return __uint_as_float(((unsigned)h) << 16);
}

// ---------------------------- QKV projection (f32) --------------------------
__global__ __launch_bounds__(256) void qkv_gemm_k(
    const float* __restrict__ feat,
    const float* __restrict__ Wq, const float* __restrict__ bq,
    const float* __restrict__ Wk, const float* __restrict__ bk,
    const float* __restrict__ Wv, const float* __restrict__ bv,
    float* __restrict__ Qo, float* __restrict__ Ko, float* __restrict__ Vo)
{
    const int z = blockIdx.z;
    const float* __restrict__ W    = (z == 0) ? Wq : (z == 1) ? Wk : Wv;
    const float* __restrict__ bias = (z == 0) ? bq : (z == 1) ? bk : bv;
    float* __restrict__ outp       = (z == 0) ? Qo : (z == 1) ? Ko : Vo;

    const int row0 = blockIdx.y * 64;
    const int col0 = blockIdx.x * 64;
    __shared__ float As[64][36];
    __shared__ float Bs[64][36];
    const int tid = threadIdx.x;
    const int tx = tid & 15, ty = tid >> 4;
    float acc[4][4] = {{0.f, 0.f, 0.f, 0.f}};

    for (int k0 = 0; k0 < Dd; k0 += 32) {
        __syncthreads();
        #pragma unroll
        for (int it = 0; it < 2; ++it) {
            int i = tid + it * 256;
            int r = i >> 3, kc = (i & 7) << 2;
            f4 a = *(const f4*)(feat + (size_t)(row0 + r) * Dd + k0 + kc);
            f4 b = *(const f4*)(W    + (size_t)(col0 + r) * Dd + k0 + kc);
            *(f4*)&As[r][kc] = a;
            *(f4*)&Bs[r][kc] = b;
        }
        __syncthreads();
        #pragma unroll
        for (int kk = 0; kk < 32; kk += 4) {
            f4 av[4], bv4[4];
            #pragma unroll
            for (int i = 0; i < 4; ++i) av[i]  = *(const f4*)&As[4 * ty + i][kk];
            #pragma unroll
            for (int j = 0; j < 4; ++j) bv4[j] = *(const f4*)&Bs[4 * tx + j][kk];
            #pragma unroll
            for (int i = 0; i < 4; ++i)
                #pragma unroll
                for (int j = 0; j < 4; ++j)
                    #pragma unroll
                    for (int c = 0; c < 4; ++c)
                        acc[i][j] = fmaf(av[i][c], bv4[j][c], acc[i][j]);
        }
    }
    #pragma unroll
    for (int i = 0; i < 4; ++i) {
        f4 o;
        #pragma unroll
        for (int j = 0; j < 4; ++j) o[j] = acc[i][j] + bias[col0 + tx * 4 + j];
        *(f4*)(outp + (size_t)(row0 + ty * 4 + i) * Dd + col0 + tx * 4) = o;
    }
}

// -------------------- pack Q/K/V into MFMA fragment order -------------------
// A/B frag (16x16x32): lane L holds row m=L&15, k = (L>>4)*8 + j (8 bf16).
// Q/K: pack[((h*96+mt)*2+kc)*512 + L*8 + j] = X[mt*16+(L&15)][h*64+kc*32+(L>>4)*8+j]
// V (B of PV, k=r, n=dout): pack[((h*48+rc)*4+dt)*512 + L*8 + j]
//                         = V[rc*32+(L>>4)*8+j][h*64+dt*16+(L&15)]
// Q pre-scaled by 0.25 (exact, power of 2).
__global__ __launch_bounds__(256) void pack_k(
    const float* __restrict__ Q, const float* __restrict__ K, const float* __restrict__ V,
    unsigned short* __restrict__ pQh, unsigned short* __restrict__ pQl,
    unsigned short* __restrict__ pKh, unsigned short* __restrict__ pKl,
    unsigned short* __restrict__ pVh, unsigned short* __restrict__ pVl)
{
    int tg = blockIdx.x * 256 + threadIdx.x;   // 98304 per type
    int type = blockIdx.y;
    int L = tg & 63;
    float x[8];
    unsigned short* oh;
    unsigned short* ol;
    if (type < 2) {
        const float* src = type ? K : Q;
        oh = type ? pKh : pQh;
        ol = type ? pKl : pQl;
        int kc = (tg >> 6) & 1;
        int mt = (tg >> 7) % 96;
        int h  = (tg >> 7) / 96;
        int row = mt * 16 + (L & 15);
        int col = h * 64 + kc * 32 + (L >> 4) * 8;
        f4 a = *(const f4*)(src + (size_t)row * Dd + col);
        f4 b = *(const f4*)(src + (size_t)row * Dd + col + 4);
        float sc = type ? 1.0f : 0.25f;
        #pragma unroll
        for (int j = 0; j < 4; ++j) { x[j] = a[j] * sc; x[4 + j] = b[j] * sc; }
    } else {
        oh = pVh; ol = pVl;
        int dt = (tg >> 6) & 3;
        int rc = (tg >> 8) % 48;
        int h  = (tg >> 8) / 48;
        int col  = h * 64 + dt * 16 + (L & 15);
        int row0 = rc * 32 + (L >> 4) * 8;
        #pragma unroll
        for (int j = 0; j < 8; ++j) x[j] = V[(size_t)(row0 + j) * Dd + col];
    }
    unsigned short hs[8], ls[8];
    #pragma unroll
    for (int j = 0; j < 8; ++j) {
        hs[j] = bf16_rne(x[j]);
        ls[j] = bf16_rne(x[j] - bf16_tof(hs[j]));
    }
    *(bf16x8*)(oh + (size_t)tg * 8) = *(bf16x8*)hs;
    *(bf16x8*)(ol + (size_t)tg * 8) = *(bf16x8*)ls;
}

// ------------------------- rel / eid init + scatter -------------------------
__global__ void init_rel_k(float* __restrict__ rel, int* __restrict__ eid)
{
    size_t i = (size_t)blockIdx.x * 256 + threadIdx.x;
    if (i < (size_t)Nn * Nn) { rel[i] = 0.f; eid[i] = -1; }
}

__global__ void norm_idx_k(const int* __restrict__ raw, int* __restrict__ idxn, int E2)
{
    int e = blockIdx.x * 256 + threadIdx.x;
    if (e >= E2) return;
    int acc = 0;
    #pragma unroll
    for (int i = 0; i < 16; ++i) acc |= raw[2 * i + 1];
    int v;
    if (acc == 0) v = raw[2 * e];
    else          v = raw[e];
    idxn[e] = v;
}

__global__ void scatter_k(const int* __restrict__ idxn, const float* __restrict__ attr,
                          float* __restrict__ rel, int* __restrict__ eid, int E)
{
    int e = blockIdx.x * 256 + threadIdx.x;
    if (e >= E) return;
    int s = idxn[e], t = idxn[E + e];
    size_t off = (size_t)s * Nn + t;
    atomicAdd(rel + off, attr[e] * SCALE_F);
    eid[off] = e;
}

// ------------------ odd-index sums (PE at rel==0 constants) -----------------
// kodd [N][H] (unscaled, for delta_k); koddT [H][N] scaled by 0.125 (for flash)
__global__ void oddsum_k(const float* __restrict__ Q, const float* __restrict__ K,
                         float* __restrict__ qodd, float* __restrict__ kodd,
                         float* __restrict__ koddT)
{
    int t = blockIdx.x * 256 + threadIdx.x;
    if (t >= 2 * Nn * Hh) return;
    const float* src = (t < Nn * Hh) ? Q : K;
    int i = (t < Nn * Hh) ? t : t - Nn * Hh;
    int n = i >> 3, h = i & 7;
    const float* row = src + (size_t)n * Dd + h * DHd;
    float s = 0.f;
    #pragma unroll
    for (int ii = 0; ii < 32; ++ii) s += row[2 * ii + 1];
    if (t < Nn * Hh) qodd[i] = s;
    else { kodd[i] = s; koddT[h * Nn + n] = 0.125f * s; }
}

// ------------------- per-edge, per-head logit corrections -------------------
// delta8[e][h] = 0.125 * ((q+k).pe(rel) - qodd - kodd)
__global__ void delta_k(const int* __restrict__ idxn, const float* __restrict__ rel,
                        const float* __restrict__ Q, const float* __restrict__ K,
                        const float* __restrict__ qodd, const float* __restrict__ kodd,
                        float* __restrict__ delta8, int E)
{
    int e = blockIdx.x * 256 + threadIdx.x;
    if (e >= E) return;
    int qi = idxn[e], ri = idxn[E + e];
    float x = rel[(size_t)qi * Nn + ri];
    float sv[32], cv[32];
    #pragma unroll
    for (int i = 0; i < 32; ++i) {
        float div = expf(-0.28782313662425572f * (float)i);
        sincosf(x * div, &sv[i], &cv[i]);
    }
    const float* qrow = Q + (size_t)qi * Dd;
    const float* krow = K + (size_t)ri * Dd;
    for (int h = 0; h < Hh; ++h) {
        float acc = 0.f;
        #pragma unroll
        for (int i = 0; i < 32; ++i) {
            float2 q2 = *(const float2*)(qrow + h * DHd + 2 * i);
            float2 k2 = *(const float2*)(krow + h * DHd + 2 * i);
            acc += (q2.x + k2.x) * sv[i] + (q2.y + k2.y) * cv[i];
        }
        delta8[(size_t)e * Hh + h] = 0.125f * (acc - qodd[qi * Hh + h] - kodd[ri * Hh + h]);
    }
}

// --------------------- flash attention, split-bf16 MFMA ---------------------
// Block = 1 wave. grid = (96 q-tiles, 8 heads, 2 splits). Per r-tile (64):
//   S (C-layout) = 6 split MFMAs per 16x16 tile; bias/softmax in C-layout;
//   P -> LDS (bf16 hi/lo) -> A-frags; PV = 6 split MFMAs per dout-tile.
// C/D: col=lane&15, row=(lane>>4)*4+reg.  A: [m=lane&15][k=(lane>>4)*8+j].
__global__ __launch_bounds__(64) void flash3_k(
    const unsigned short* __restrict__ pQh, const unsigned short* __restrict__ pQl,
    const unsigned short* __restrict__ pKh, const unsigned short* __restrict__ pKl,
    const unsigned short* __restrict__ pVh, const unsigned short* __restrict__ pVl,
    const int* __restrict__ eid, const float* __restrict__ delta8,
    const float* __restrict__ koddT,
    float* __restrict__ Opart, float* __restrict__ Mpart, float* __restrict__ Lpart)
{
    const int qt = blockIdx.x, h = blockIdx.y, s = blockIdx.z;
    const int L = threadIdx.x, quad = L >> 4, l15 = L & 15;
    const int q0 = qt * 16;
    __shared__ unsigned short phi[16][80];
    __shared__ unsigned short plo[16][80];

    bf16x8 qh[2], ql[2];
    #pragma unroll
    for (int kc = 0; kc < 2; ++kc) {
        size_t off = ((size_t)((h * 96 + qt) * 2 + kc)) * 512 + L * 8;
        qh[kc] = *(const bf16x8*)(pQh + off);
        ql[kc] = *(const bf16x8*)(pQl + off);
    }

    float m_[4], l_[4];
    f32x4 O[4];
    #pragma unroll
    for (int r = 0; r < 4; ++r) { m_[r] = -3.0e38f; l_[r] = 0.f; O[r] = (f32x4){0.f,0.f,0.f,0.f}; }

    const int Tbase = s * 12;           // 24 r-tiles of 64, split in 2
    for (int T = 0; T < 12; ++T) {
        const int r0 = (Tbase + T) * 64;

        // ---- S = 0.25 * Q K^T  (Q pre-scaled) ----
        f32x4 S[4];
        #pragma unroll
        for (int nt = 0; nt < 4; ++nt) {
            int rt = (r0 >> 4) + nt;
            size_t b0 = ((size_t)((h * 96 + rt) * 2 + 0)) * 512 + L * 8;
            bf16x8 kh0 = *(const bf16x8*)(pKh + b0);
            bf16x8 kh1 = *(const bf16x8*)(pKh + b0 + 512);
            bf16x8 kl0 = *(const bf16x8*)(pKl + b0);
            bf16x8 kl1 = *(const bf16x8*)(pKl + b0 + 512);
            f32x4 a = {0.f, 0.f, 0.f, 0.f};
            a = __builtin_amdgcn_mfma_f32_16x16x32_bf16(qh[0], kh0, a, 0, 0, 0);
            a = __builtin_amdgcn_mfma_f32_16x16x32_bf16(qh[1], kh1, a, 0, 0, 0);
            a = __builtin_amdgcn_mfma_f32_16x16x32_bf16(qh[0], kl0, a, 0, 0, 0);
            a = __builtin_amdgcn_mfma_f32_16x16x32_bf16(qh[1], kl1, a, 0, 0, 0);
            a = __builtin_amdgcn_mfma_f32_16x16x32_bf16(ql[0], kh0, a, 0, 0, 0);
            a = __builtin_amdgcn_mfma_f32_16x16x32_bf16(ql[1], kh1, a, 0, 0, 0);
            S[nt] = a;
        }

        // ---- bias: + 0.125*kodd[r] + 0.125*delta[eid] ----
        float lg[4][4];
        #pragma unroll
        for (int nt = 0; nt < 4; ++nt) {
            float kv = koddT[h * Nn + r0 + nt * 16 + l15];
            #pragma unroll
            for (int reg = 0; reg < 4; ++reg) {
                int qg = q0 + quad * 4 + reg;
                int e = eid[(size_t)qg * Nn + r0 + nt * 16 + l15];
                float v = S[nt][reg] + kv;
                if (e >= 0) v += delta8[(size_t)e * Hh + h];
                lg[nt][reg] = v;
            }
        }

        // ---- online softmax (rows live across 16 lanes; 4 rows per lane) ----
        float al[4];
        #pragma unroll
        for (int reg = 0; reg < 4; ++reg) {
            float mx = fmaxf(fmaxf(lg[0][reg], lg[1][reg]), fmaxf(lg[2][reg], lg[3][reg]));
            #pragma unroll
            for (int o = 1; o < 16; o <<= 1) mx = fmaxf(mx, __shfl_xor(mx, o));
            float mn = fmaxf(m_[reg], mx);
            al[reg] = __expf(m_[reg] - mn);
            float p[4], sp = 0.f;
            #pragma unroll
            for (int nt = 0; nt < 4; ++nt) { p[nt] = __expf(lg[nt][reg] - mn); sp += p[nt]; }
            #pragma unroll
            for (int o = 1; o < 16; o <<= 1) sp += __shfl_xor(sp, o);
            l_[reg] = l_[reg] * al[reg] + sp;
            m_[reg] = mn;
            #pragma unroll
            for (int nt = 0; nt < 4; ++nt) {
                unsigned short hi = bf16_rne(p[nt]);
                phi[quad * 4 + reg][nt * 16 + l15] = hi;
                plo[quad * 4 + reg][nt * 16 + l15] = bf16_rne(p[nt] - bf16_tof(hi));
            }
        }
        #pragma unroll
        for (int dt = 0; dt < 4; ++dt)
            #pragma unroll
            for (int reg = 0; reg < 4; ++reg) O[dt][reg] *= al[reg];

        // ---- P A-frags from LDS (in-wave DS ordering, no barrier) ----
        bf16x8 ph[2], pl[2];
        #pragma unroll
        for (int kc2 = 0; kc2 < 2; ++kc2) {
            ph[kc2] = *(const bf16x8*)&phi[l15][kc2 * 32 + quad * 8];
            pl[kc2] = *(const bf16x8*)&plo[l15][kc2 * 32 + quad * 8];
        }

        // ---- O += P V ----
        #pragma unroll
        for (int dt = 0; dt < 4; ++dt) {
            size_t vb = ((size_t)((h * 48 + (r0 >> 5)) * 4 + dt)) * 512 + L * 8;
            bf16x8 vh0 = *(const bf16x8*)(pVh + vb);
            bf16x8 vh1 = *(const bf16x8*)(pVh + vb + 2048);
            bf16x8 vl0 = *(const bf16x8*)(pVl + vb);
            bf16x8 vl1 = *(const bf16x8*)(pVl + vb + 2048);
            f32x4 a = O[dt];
            a = __builtin_amdgcn_mfma_f32_16x16x32_bf16(ph[0], vh0, a, 0, 0, 0);
            a = __builtin_amdgcn_mfma_f32_16x16x32_bf16(ph[1], vh1, a, 0, 0, 0);
            a = __builtin_amdgcn_mfma_f32_16x16x32_bf16(ph[0], vl0, a, 0, 0, 0);
            a = __builtin_amdgcn_mfma_f32_16x16x32_bf16(ph[1], vl1, a, 0, 0, 0);
            a = __builtin_amdgcn_mfma_f32_16x16x32_bf16(pl[0], vh0, a, 0, 0, 0);
            a = __builtin_amdgcn_mfma_f32_16x16x32_bf16(pl[1], vh1, a, 0, 0, 0);
            O[dt] = a;
        }
    }

    // ---- store partials ----
    #pragma unroll
    for (int dt = 0; dt < 4; ++dt)
        #pragma unroll
        for (int reg = 0; reg < 4; ++reg)
            Opart[((size_t)(s * Hh + h) * Nn + q0 + quad * 4 + reg) * 64 + dt * 16 + l15] = O[dt][reg];
    if (l15 == 0) {
        #pragma unroll
        for (int reg = 0; reg < 4; ++reg) {
            size_t mi = (size_t)(s * Hh + h) * Nn + q0 + quad * 4 + reg;
            Mpart[mi] = m_[reg];
            Lpart[mi] = l_[reg];
        }
    }
}

// ----------------------------- split-K combine ------------------------------
__global__ __launch_bounds__(256) void combine_k(
    const float* __restrict__ Opart, const float* __restrict__ Mpart,
    const float* __restrict__ Lpart, float* __restrict__ outbuf)
{
    int t = blockIdx.x * 256 + threadIdx.x;
    if (t >= Nn * Dd) return;
    int q = t >> 9, c = t & 511, h = c >> 6, d = c & 63;
    size_t i0 = (size_t)h * Nn + q;
    size_t i1 = (size_t)(Hh + h) * Nn + q;
    float m0 = Mpart[i0], m1 = Mpart[i1];
    float ms = fmaxf(m0, m1);
    float w0 = __expf(m0 - ms), w1 = __expf(m1 - ms);
    float l = Lpart[i0] * w0 + Lpart[i1] * w1;
    float o = Opart[i0 * 64 + d] * w0 + Opart[i1 * 64 + d] * w1;
    outbuf[t] = o / l;
}

// ------------------------------ max pool (2-stage) --------------------------
__global__ __launch_bounds__(128) void mp1_k(const float* __restrict__ outbuf,
                                             float* __restrict__ partial)
{
    const int b = blockIdx.x;
    const int t = threadIdx.x;
    f4 mx = {-3.0e38f, -3.0e38f, -3.0e38f, -3.0e38f};
    for (int r = 0; r < 64; ++r) {
        f4 v = *(const f4*)(outbuf + (size_t)(64 * b + r) * Dd + 4 * t);
        #pragma unroll
        for (int c = 0; c < 4; ++c) mx[c] = fmaxf(mx[c], v[c]);
    }
    *(f4*)(partial + (size_t)b * Dd + 4 * t) = mx;
}

__global__ __launch_bounds__(128) void mp2_k(const float* __restrict__ partial,
                                             float* __restrict__ outp)
{
    const int t = threadIdx.x;
    f4 mx = {-3.0e38f, -3.0e38f, -3.0e38f, -3.0e38f};
    for (int b = 0; b < 24; ++b) {
        f4 v = *(const f4*)(partial + (size_t)b * Dd + 4 * t);
        #pragma unroll
        for (int c = 0; c < 4; ++c) mx[c] = fmaxf(mx[c], v[c]);
    }
    *(f4*)(outp + 4 * t) = mx;
}

// ---------------------------------------------------------------------------
extern "C" void kernel_launch(void* const* d_in, const int* in_sizes, int n_in,
                              void* d_out, int out_size, void* d_ws, size_t ws_size,
                              hipStream_t stream)
{
    const float* feat   = (const float*)d_in[0];
    const int*   rawidx = (const int*)d_in[1];
    const float* attr   = (const float*)d_in[2];
    const float* Wq = (const float*)d_in[4];
    const float* bq = (const float*)d_in[5];
    const float* Wk = (const float*)d_in[6];
    const float* bk = (const float*)d_in[7];
    const float* Wv = (const float*)d_in[8];
    const float* bv = (const float*)d_in[9];
    float* outp = (float*)d_out;
    const int E = in_sizes[2];

    const size_t ND_ = (size_t)Nn * Dd;      // 786432
    const size_t NN_ = (size_t)Nn * Nn;      // 2359296
    const size_t PK_ = (size_t)Hh * 96 * 2 * 512;   // 786432 bf16 els per pack array
    float* ws    = (float*)d_ws;
    float* Q     = ws;
    float* K     = Q + ND_;
    float* V     = K + ND_;
    float* relz  = V + ND_;                  // rel; later Opart(1572864)+outbuf(786432)
    int*   eid   = (int*)(relz + NN_);
    float* delta8 = (float*)(eid + NN_);
    float* qodd  = delta8 + (size_t)E * Hh;
    float* kodd  = qodd + (size_t)Nn * Hh;
    float* koddT = kodd + (size_t)Nn * Hh;
    int*   idxn  = (int*)(koddT + (size_t)Nn * Hh);
    unsigned short* pQh = (unsigned short*)(idxn + 2 * E);
    unsigned short* pQl = pQh + PK_;
    unsigned short* pKh = pQl + PK_;
    unsigned short* pKl = pKh + PK_;
    unsigned short* pVh = pKl + PK_;
    unsigned short* pVl = pVh + PK_;
    float* Mpart = (float*)(pVl + PK_);
    float* Lpart = Mpart + 2 * Hh * Nn;
    float* mpart = Lpart + 2 * Hh * Nn;      // maxpool stage-1 partials
    float* rel    = relz;
    float* Opart  = relz;                    // aliases rel (dead after delta_k)
    float* outbuf = relz + (size_t)2 * Hh * Nn * 64;

    qkv_gemm_k<<<dim3(Dd / 64, Nn / 64, 3), 256, 0, stream>>>(feat, Wq, bq, Wk, bk, Wv, bv, Q, K, V);
    init_rel_k<<<(int)((NN_ + 255) / 256), 256, 0, stream>>>(rel, eid);
    norm_idx_k<<<(2 * E + 255) / 256, 256, 0, stream>>>(rawidx, idxn, 2 * E);
    scatter_k<<<(E + 255) / 256, 256, 0, stream>>>(idxn, attr, rel, eid, E);
    oddsum_k<<<(2 * Nn * Hh + 255) / 256, 256, 0, stream>>>(Q, K, qodd, kodd, koddT);
    delta_k<<<(E + 255) / 256, 256, 0, stream>>>(idxn, rel, Q, K, qodd, kodd, delta8, E);
    pack_k<<<dim3(384, 3), 256, 0, stream>>>(Q, K, V, pQh, pQl, pKh, pKl, pVh, pVl);
    flash3_k<<<dim3(96, 8, 2), 64, 0, stream>>>(pQh, pQl, pKh, pKl, pVh, pVl,
                                                eid, delta8, koddT, Opart, Mpart, Lpart);
    combine_k<<<(int)((ND_ + 255) / 256), 256, 0, stream>>>(Opart, Mpart, Lpart, outbuf);
    mp1_k<<<24, 128, 0, stream>>>(outbuf, mpart);
    mp2_k<<<1, 128, 0, stream>>>(mpart, outp);
}

// Round 4
// 269.923 us; speedup vs baseline: 2.5625x; 1.4432x over previous
//
#include <hip/hip_runtime.h>
#include <cmath>

// ---------------------------------------------------------------------------
// DistanceAwareMultiheadAttention  (N=1536, E=49152, D=512, H=8, DH=64)
//
// Round 4:
//  - delta_k: one thread per (edge, head) + fast __sincosf  (was 172 us,
//    1 thread/edge + libm sincos, latency-bound at 0.13% occupancy)
//  - flash: split-K 4 (3 waves/SIMD), branchless delta gathers, software
//    prefetch of eid/koddT/delta8 one r-tile ahead
//  - combine fused with maxpool stage 1
// ---------------------------------------------------------------------------

constexpr int Nn  = 1536;
constexpr int Dd  = 512;
constexpr int Hh  = 8;
constexpr int DHd = 64;
constexpr int SPLITS = 4;
constexpr float SCALE_F = 362.03867196751236f;   // 256*sqrt(2)

typedef float f4 __attribute__((ext_vector_type(4)));
typedef __attribute__((ext_vector_type(4))) float f32x4;
typedef __attribute__((ext_vector_type(8))) short bf16x8;

__device__ inline unsigned short bf16_rne(float x) {
    unsigned u = __float_as_uint(x);
    unsigned r = u + 0x7fff + ((u >> 16) & 1);
    return (unsigned short)(r >> 16);
}
__device__ inline float bf16_tof(unsigned short h) {
    return __uint_as_float(((unsigned)h) << 16);
}

// ---------------------------- QKV projection (f32) --------------------------
__global__ __launch_bounds__(256) void qkv_gemm_k(
    const float* __restrict__ feat,
    const float* __restrict__ Wq, const float* __restrict__ bq,
    const float* __restrict__ Wk, const float* __restrict__ bk,
    const float* __restrict__ Wv, const float* __restrict__ bv,
    float* __restrict__ Qo, float* __restrict__ Ko, float* __restrict__ Vo)
{
    const int z = blockIdx.z;
    const float* __restrict__ W    = (z == 0) ? Wq : (z == 1) ? Wk : Wv;
    const float* __restrict__ bias = (z == 0) ? bq : (z == 1) ? bk : bv;
    float* __restrict__ outp       = (z == 0) ? Qo : (z == 1) ? Ko : Vo;

    const int row0 = blockIdx.y * 64;
    const int col0 = blockIdx.x * 64;
    __shared__ float As[64][36];
    __shared__ float Bs[64][36];
    const int tid = threadIdx.x;
    const int tx = tid & 15, ty = tid >> 4;
    float acc[4][4] = {{0.f, 0.f, 0.f, 0.f}};

    for (int k0 = 0; k0 < Dd; k0 += 32) {
        __syncthreads();
        #pragma unroll
        for (int it = 0; it < 2; ++it) {
            int i = tid + it * 256;
            int r = i >> 3, kc = (i & 7) << 2;
            f4 a = *(const f4*)(feat + (size_t)(row0 + r) * Dd + k0 + kc);
            f4 b = *(const f4*)(W    + (size_t)(col0 + r) * Dd + k0 + kc);
            *(f4*)&As[r][kc] = a;
            *(f4*)&Bs[r][kc] = b;
        }
        __syncthreads();
        #pragma unroll
        for (int kk = 0; kk < 32; kk += 4) {
            f4 av[4], bv4[4];
            #pragma unroll
            for (int i = 0; i < 4; ++i) av[i]  = *(const f4*)&As[4 * ty + i][kk];
            #pragma unroll
            for (int j = 0; j < 4; ++j) bv4[j] = *(const f4*)&Bs[4 * tx + j][kk];
            #pragma unroll
            for (int i = 0; i < 4; ++i)
                #pragma unroll
                for (int j = 0; j < 4; ++j)
                    #pragma unroll
                    for (int c = 0; c < 4; ++c)
                        acc[i][j] = fmaf(av[i][c], bv4[j][c], acc[i][j]);
        }
    }
    #pragma unroll
    for (int i = 0; i < 4; ++i) {
        f4 o;
        #pragma unroll
        for (int j = 0; j < 4; ++j) o[j] = acc[i][j] + bias[col0 + tx * 4 + j];
        *(f4*)(outp + (size_t)(row0 + ty * 4 + i) * Dd + col0 + tx * 4) = o;
    }
}

// -------------------- pack Q/K/V into MFMA fragment order -------------------
__global__ __launch_bounds__(256) void pack_k(
    const float* __restrict__ Q, const float* __restrict__ K, const float* __restrict__ V,
    unsigned short* __restrict__ pQh, unsigned short* __restrict__ pQl,
    unsigned short* __restrict__ pKh, unsigned short* __restrict__ pKl,
    unsigned short* __restrict__ pVh, unsigned short* __restrict__ pVl)
{
    int tg = blockIdx.x * 256 + threadIdx.x;   // 98304 per type
    int type = blockIdx.y;
    int L = tg & 63;
    float x[8];
    unsigned short* oh;
    unsigned short* ol;
    if (type < 2) {
        const float* src = type ? K : Q;
        oh = type ? pKh : pQh;
        ol = type ? pKl : pQl;
        int kc = (tg >> 6) & 1;
        int mt = (tg >> 7) % 96;
        int h  = (tg >> 7) / 96;
        int row = mt * 16 + (L & 15);
        int col = h * 64 + kc * 32 + (L >> 4) * 8;
        f4 a = *(const f4*)(src + (size_t)row * Dd + col);
        f4 b = *(const f4*)(src + (size_t)row * Dd + col + 4);
        float sc = type ? 1.0f : 0.25f;
        #pragma unroll
        for (int j = 0; j < 4; ++j) { x[j] = a[j] * sc; x[4 + j] = b[j] * sc; }
    } else {
        oh = pVh; ol = pVl;
        int dt = (tg >> 6) & 3;
        int rc = (tg >> 8) % 48;
        int h  = (tg >> 8) / 48;
        int col  = h * 64 + dt * 16 + (L & 15);
        int row0 = rc * 32 + (L >> 4) * 8;
        #pragma unroll
        for (int j = 0; j < 8; ++j) x[j] = V[(size_t)(row0 + j) * Dd + col];
    }
    unsigned short hs[8], ls[8];
    #pragma unroll
    for (int j = 0; j < 8; ++j) {
        hs[j] = bf16_rne(x[j]);
        ls[j] = bf16_rne(x[j] - bf16_tof(hs[j]));
    }
    *(bf16x8*)(oh + (size_t)tg * 8) = *(bf16x8*)hs;
    *(bf16x8*)(ol + (size_t)tg * 8) = *(bf16x8*)ls;
}

// ------------------------- rel / eid init + scatter -------------------------
__global__ void init_rel_k(float* __restrict__ rel, int* __restrict__ eid)
{
    size_t i = (size_t)blockIdx.x * 256 + threadIdx.x;
    if (i < (size_t)Nn * Nn) { rel[i] = 0.f; eid[i] = -1; }
}

__global__ void norm_idx_k(const int* __restrict__ raw, int* __restrict__ idxn, int E2)
{
    int e = blockIdx.x * 256 + threadIdx.x;
    if (e >= E2) return;
    int acc = 0;
    #pragma unroll
    for (int i = 0; i < 16; ++i) acc |= raw[2 * i + 1];
    int v;
    if (acc == 0) v = raw[2 * e];
    else          v = raw[e];
    idxn[e] = v;
}

__global__ void scatter_k(const int* __restrict__ idxn, const float* __restrict__ attr,
                          float* __restrict__ rel, int* __restrict__ eid, int E)
{
    int e = blockIdx.x * 256 + threadIdx.x;
    if (e >= E) return;
    int s = idxn[e], t = idxn[E + e];
    size_t off = (size_t)s * Nn + t;
    atomicAdd(rel + off, attr[e] * SCALE_F);
    eid[off] = e;
}

// ------------------ odd-index sums (PE at rel==0 constants) -----------------
__global__ void oddsum_k(const float* __restrict__ Q, const float* __restrict__ K,
                         float* __restrict__ qodd, float* __restrict__ kodd,
                         float* __restrict__ koddT)
{
    int t = blockIdx.x * 256 + threadIdx.x;
    if (t >= 2 * Nn * Hh) return;
    const float* src = (t < Nn * Hh) ? Q : K;
    int i = (t < Nn * Hh) ? t : t - Nn * Hh;
    int n = i >> 3, h = i & 7;
    const float* row = src + (size_t)n * Dd + h * DHd;
    float s = 0.f;
    #pragma unroll
    for (int ii = 0; ii < 32; ++ii) s += row[2 * ii + 1];
    if (t < Nn * Hh) qodd[i] = s;
    else { kodd[i] = s; koddT[h * Nn + n] = 0.125f * s; }
}

// ------------------- per-edge, per-head logit corrections -------------------
// One thread per (edge, head); fast sincos (hw v_sin/v_cos via __sincosf).
__global__ __launch_bounds__(256) void delta_k(
    const int* __restrict__ idxn, const float* __restrict__ rel,
    const float* __restrict__ Q, const float* __restrict__ K,
    const float* __restrict__ qodd, const float* __restrict__ kodd,
    float* __restrict__ delta8, int E)
{
    int t = blockIdx.x * 256 + threadIdx.x;
    if (t >= E * Hh) return;
    int e = t >> 3, h = t & 7;
    int qi = idxn[e], ri = idxn[E + e];
    float x = rel[(size_t)qi * Nn + ri];
    const float* qrow = Q + (size_t)qi * Dd + h * DHd;
    const float* krow = K + (size_t)ri * Dd + h * DHd;
    float acc = 0.f;
    #pragma unroll
    for (int i = 0; i < 32; i += 2) {
        float d0 = expf(-0.28782313662425572f * (float)i);       // compile-time
        float d1 = expf(-0.28782313662425572f * (float)(i + 1)); // compile-time
        float s0, c0, s1, c1;
        __sincosf(x * d0, &s0, &c0);
        __sincosf(x * d1, &s1, &c1);
        f4 q4 = *(const f4*)(qrow + 2 * i);
        f4 k4 = *(const f4*)(krow + 2 * i);
        acc += (q4[0] + k4[0]) * s0 + (q4[1] + k4[1]) * c0
             + (q4[2] + k4[2]) * s1 + (q4[3] + k4[3]) * c1;
    }
    delta8[(size_t)e * Hh + h] = 0.125f * (acc - qodd[qi * Hh + h] - kodd[ri * Hh + h]);
}

// --------------------- flash attention, split-bf16 MFMA ---------------------
// Block = 1 wave; grid (96 q-tiles, 8 heads, 4 splits) -> 3 waves/SIMD.
// eid/koddT prefetched one r-tile ahead; delta8 gathered branchlessly one
// tile ahead. C/D: col=lane&15, row=(lane>>4)*4+reg. A: [m=l15][k=quad*8+j].
__global__ __launch_bounds__(64) void flash4_k(
    const unsigned short* __restrict__ pQh, const unsigned short* __restrict__ pQl,
    const unsigned short* __restrict__ pKh, const unsigned short* __restrict__ pKl,
    const unsigned short* __restrict__ pVh, const unsigned short* __restrict__ pVl,
    const int* __restrict__ eid, const float* __restrict__ delta8,
    const float* __restrict__ koddT,
    float* __restrict__ Opart, float* __restrict__ Mpart, float* __restrict__ Lpart)
{
    const int qt = blockIdx.x, h = blockIdx.y, s = blockIdx.z;
    const int L = threadIdx.x, quad = L >> 4, l15 = L & 15;
    const int q0 = qt * 16;
    __shared__ unsigned short phi[16][80];
    __shared__ unsigned short plo[16][80];

    bf16x8 qh[2], ql[2];
    #pragma unroll
    for (int kc = 0; kc < 2; ++kc) {
        size_t off = ((size_t)((h * 96 + qt) * 2 + kc)) * 512 + L * 8;
        qh[kc] = *(const bf16x8*)(pQh + off);
        ql[kc] = *(const bf16x8*)(pQl + off);
    }

    float m_[4], l_[4];
    f32x4 O[4];
    #pragma unroll
    for (int r = 0; r < 4; ++r) { m_[r] = -3.0e38f; l_[r] = 0.f; O[r] = (f32x4){0.f,0.f,0.f,0.f}; }

    const int NT = 24 / SPLITS;         // 6 r-tiles per split
    const int Tbase = s * NT;

    // ---- prologue: meta for tile 0 ----
    int   ecur[16];
    float kvcur[4], dcur[16];
    {
        const int r0 = Tbase * 64;
        #pragma unroll
        for (int nt = 0; nt < 4; ++nt) {
            kvcur[nt] = koddT[h * Nn + r0 + nt * 16 + l15];
            #pragma unroll
            for (int reg = 0; reg < 4; ++reg)
                ecur[nt * 4 + reg] = eid[(size_t)(q0 + quad * 4 + reg) * Nn + r0 + nt * 16 + l15];
        }
        #pragma unroll
        for (int i = 0; i < 16; ++i) {
            int e = ecur[i];
            float d = delta8[(size_t)(e < 0 ? 0 : e) * Hh + h];
            dcur[i] = (e >= 0) ? d : 0.f;
        }
    }

    for (int T = 0; T < NT; ++T) {
        const int r0 = (Tbase + T) * 64;
        const bool more = (T + 1 < NT);

        // ---- prefetch next tile's eid + koddT (in flight across this tile) ----
        int   enxt[16];
        float kvnxt[4];
        if (more) {
            const int r1 = r0 + 64;
            #pragma unroll
            for (int nt = 0; nt < 4; ++nt) {
                kvnxt[nt] = koddT[h * Nn + r1 + nt * 16 + l15];
                #pragma unroll
                for (int reg = 0; reg < 4; ++reg)
                    enxt[nt * 4 + reg] = eid[(size_t)(q0 + quad * 4 + reg) * Nn + r1 + nt * 16 + l15];
            }
        }

        // ---- issue V loads for this tile early (consumed after softmax) ----
        bf16x8 vh0[4], vh1[4], vl0[4], vl1[4];
        #pragma unroll
        for (int dt = 0; dt < 4; ++dt) {
            size_t vb = ((size_t)((h * 48 + (r0 >> 5)) * 4 + dt)) * 512 + L * 8;
            vh0[dt] = *(const bf16x8*)(pVh + vb);
            vh1[dt] = *(const bf16x8*)(pVh + vb + 2048);
            vl0[dt] = *(const bf16x8*)(pVl + vb);
            vl1[dt] = *(const bf16x8*)(pVl + vb + 2048);
        }

        // ---- S = 0.25 * Q K^T  (Q pre-scaled; split-bf16, 6 MFMAs/tile) ----
        f32x4 S[4];
        #pragma unroll
        for (int nt = 0; nt < 4; ++nt) {
            int rt = (r0 >> 4) + nt;
            size_t b0 = ((size_t)((h * 96 + rt) * 2 + 0)) * 512 + L * 8;
            bf16x8 kh0 = *(const bf16x8*)(pKh + b0);
            bf16x8 kh1 = *(const bf16x8*)(pKh + b0 + 512);
            bf16x8 kl0 = *(const bf16x8*)(pKl + b0);
            bf16x8 kl1 = *(const bf16x8*)(pKl + b0 + 512);
            f32x4 a = {0.f, 0.f, 0.f, 0.f};
            a = __builtin_amdgcn_mfma_f32_16x16x32_bf16(qh[0], kh0, a, 0, 0, 0);
            a = __builtin_amdgcn_mfma_f32_16x16x32_bf16(qh[1], kh1, a, 0, 0, 0);
            a = __builtin_amdgcn_mfma_f32_16x16x32_bf16(qh[0], kl0, a, 0, 0, 0);
            a = __builtin_amdgcn_mfma_f32_16x16x32_bf16(qh[1], kl1, a, 0, 0, 0);
            a = __builtin_amdgcn_mfma_f32_16x16x32_bf16(ql[0], kh0, a, 0, 0, 0);
            a = __builtin_amdgcn_mfma_f32_16x16x32_bf16(ql[1], kh1, a, 0, 0, 0);
            S[nt] = a;
        }

        // ---- bias from prefetched kv/delta (no global latency here) ----
        float lg[4][4];
        #pragma unroll
        for (int nt = 0; nt < 4; ++nt)
            #pragma unroll
            for (int reg = 0; reg < 4; ++reg)
                lg[nt][reg] = S[nt][reg] + kvcur[nt] + dcur[nt * 4 + reg];

        // ---- online softmax (rows across 16 lanes; 4 rows per lane) ----
        float al[4];
        #pragma unroll
        for (int reg = 0; reg < 4; ++reg) {
            float mx = fmaxf(fmaxf(lg[0][reg], lg[1][reg]), fmaxf(lg[2][reg], lg[3][reg]));
            #pragma unroll
            for (int o = 1; o < 16; o <<= 1) mx = fmaxf(mx, __shfl_xor(mx, o));
            float mn = fmaxf(m_[reg], mx);
            al[reg] = __expf(m_[reg] - mn);
            float p[4], sp = 0.f;
            #pragma unroll
            for (int nt = 0; nt < 4; ++nt) { p[nt] = __expf(lg[nt][reg] - mn); sp += p[nt]; }
            #pragma unroll
            for (int o = 1; o < 16; o <<= 1) sp += __shfl_xor(sp, o);
            l_[reg] = l_[reg] * al[reg] + sp;
            m_[reg] = mn;
            #pragma unroll
            for (int nt = 0; nt < 4; ++nt) {
                unsigned short hi = bf16_rne(p[nt]);
                phi[quad * 4 + reg][nt * 16 + l15] = hi;
                plo[quad * 4 + reg][nt * 16 + l15] = bf16_rne(p[nt] - bf16_tof(hi));
            }
        }
        #pragma unroll
        for (int dt = 0; dt < 4; ++dt)
            #pragma unroll
            for (int reg = 0; reg < 4; ++reg) O[dt][reg] *= al[reg];

        // ---- P A-frags from LDS (single wave: DS in-order, no barrier) ----
        bf16x8 ph[2], pl[2];
        #pragma unroll
        for (int kc2 = 0; kc2 < 2; ++kc2) {
            ph[kc2] = *(const bf16x8*)&phi[l15][kc2 * 32 + quad * 8];
            pl[kc2] = *(const bf16x8*)&plo[l15][kc2 * 32 + quad * 8];
        }

        // ---- O += P V ----
        #pragma unroll
        for (int dt = 0; dt < 4; ++dt) {
            f32x4 a = O[dt];
            a = __builtin_amdgcn_mfma_f32_16x16x32_bf16(ph[0], vh0[dt], a, 0, 0, 0);
            a = __builtin_amdgcn_mfma_f32_16x16x32_bf16(ph[1], vh1[dt], a, 0, 0, 0);
            a = __builtin_amdgcn_mfma_f32_16x16x32_bf16(ph[0], vl0[dt], a, 0, 0, 0);
            a = __builtin_amdgcn_mfma_f32_16x16x32_bf16(ph[1], vl1[dt], a, 0, 0, 0);
            a = __builtin_amdgcn_mfma_f32_16x16x32_bf16(pl[0], vh0[dt], a, 0, 0, 0);
            a = __builtin_amdgcn_mfma_f32_16x16x32_bf16(pl[1], vh1[dt], a, 0, 0, 0);
            O[dt] = a;
        }

        // ---- gather next tile's delta (eid prefetch has landed by now) ----
        if (more) {
            #pragma unroll
            for (int i = 0; i < 16; ++i) {
                int e = enxt[i];
                float d = delta8[(size_t)(e < 0 ? 0 : e) * Hh + h];
                dcur[i] = (e >= 0) ? d : 0.f;
                ecur[i] = e;
            }
            #pragma unroll
            for (int nt = 0; nt < 4; ++nt) kvcur[nt] = kvnxt[nt];
        }
    }

    // ---- store partials ----
    #pragma unroll
    for (int dt = 0; dt < 4; ++dt)
        #pragma unroll
        for (int reg = 0; reg < 4; ++reg)
            Opart[((size_t)(s * Hh + h) * Nn + q0 + quad * 4 + reg) * 64 + dt * 16 + l15] = O[dt][reg];
    if (l15 == 0) {
        #pragma unroll
        for (int reg = 0; reg < 4; ++reg) {
            size_t mi = (size_t)(s * Hh + h) * Nn + q0 + quad * 4 + reg;
            Mpart[mi] = m_[reg];
            Lpart[mi] = l_[reg];
        }
    }
}

// ------------------- split-K combine fused with maxpool stage 1 -------------
// 96 blocks x 256 thr: block = 16 q-rows; thread (cg = (t&127)*4 cols, rh=t>>7).
__global__ __launch_bounds__(256) void combine_mp_k(
    const float* __restrict__ Opart, const float* __restrict__ Mpart,
    const float* __restrict__ Lpart, float* __restrict__ partial)
{
    const int b = blockIdx.x;
    const int t = threadIdx.x;
    const int cg = (t & 127) * 4;
    const int h = cg >> 6, d = cg & 63;
    const int rh = t >> 7;
    f4 mx = {-3.0e38f, -3.0e38f, -3.0e38f, -3.0e38f};
    for (int r = 0; r < 8; ++r) {
        int q = b * 16 + rh * 8 + r;
        float m[SPLITS], ms = -3.0e38f;
        #pragma unroll
        for (int s2 = 0; s2 < SPLITS; ++s2) {
            m[s2] = Mpart[(size_t)(s2 * Hh + h) * Nn + q];
            ms = fmaxf(ms, m[s2]);
        }
        float l = 0.f;
        f4 o = {0.f, 0.f, 0.f, 0.f};
        #pragma unroll
        for (int s2 = 0; s2 < SPLITS; ++s2) {
            float w = __expf(m[s2] - ms);
            l += Lpart[(size_t)(s2 * Hh + h) * Nn + q] * w;
            f4 ov = *(const f4*)(Opart + ((size_t)(s2 * Hh + h) * Nn + q) * 64 + d);
            #pragma unroll
            for (int c = 0; c < 4; ++c) o[c] += w * ov[c];
        }
        float inv = 1.0f / l;
        #pragma unroll
        for (int c = 0; c < 4; ++c) mx[c] = fmaxf(mx[c], o[c] * inv);
    }
    *(f4*)(partial + (size_t)(b * 2 + rh) * 512 + cg) = mx;
}

__global__ __launch_bounds__(128) void mp2_k(const float* __restrict__ partial,
                                             float* __restrict__ outp)
{
    const int t = threadIdx.x;
    f4 mx = {-3.0e38f, -3.0e38f, -3.0e38f, -3.0e38f};
    for (int b = 0; b < 192; ++b) {
        f4 v = *(const f4*)(partial + (size_t)b * 512 + 4 * t);
        #pragma unroll
        for (int c = 0; c < 4; ++c) mx[c] = fmaxf(mx[c], v[c]);
    }
    *(f4*)(outp + 4 * t) = mx;
}

// ---------------------------------------------------------------------------
extern "C" void kernel_launch(void* const* d_in, const int* in_sizes, int n_in,
                              void* d_out, int out_size, void* d_ws, size_t ws_size,
                              hipStream_t stream)
{
    const float* feat   = (const float*)d_in[0];
    const int*   rawidx = (const int*)d_in[1];
    const float* attr   = (const float*)d_in[2];
    const float* Wq = (const float*)d_in[4];
    const float* bq = (const float*)d_in[5];
    const float* Wk = (const float*)d_in[6];
    const float* bk = (const float*)d_in[7];
    const float* Wv = (const float*)d_in[8];
    const float* bv = (const float*)d_in[9];
    float* outp = (float*)d_out;
    const int E = in_sizes[2];

    const size_t ND_ = (size_t)Nn * Dd;            // 786432
    const size_t NN_ = (size_t)Nn * Nn;            // 2359296
    const size_t PK_ = (size_t)Hh * 96 * 2 * 512;  // 786432 bf16 per pack array
    float* ws    = (float*)d_ws;
    float* Q     = ws;                    // 786432
    float* K     = Q + ND_;               // 786432
    float* V     = K + ND_;               // 786432
    float* rel   = V + ND_;               // 2359296
    int*   eid   = (int*)(rel + NN_);     // 2359296
    float* delta8 = (float*)(eid + NN_);  // 393216
    float* qodd  = delta8 + (size_t)E * Hh;
    float* kodd  = qodd + (size_t)Nn * Hh;
    float* koddT = kodd + (size_t)Nn * Hh;
    int*   idxn  = (int*)(koddT + (size_t)Nn * Hh);
    unsigned short* pQh = (unsigned short*)(idxn + 2 * E);
    unsigned short* pQl = pQh + PK_;
    unsigned short* pKh = pQl + PK_;
    unsigned short* pKl = pKh + PK_;
    unsigned short* pVh = pKl + PK_;
    unsigned short* pVl = pVh + PK_;
    float* Mpart = (float*)(pVl + PK_);                    // SPLITS*Hh*Nn = 49152
    float* Lpart = Mpart + (size_t)SPLITS * Hh * Nn;       // 49152
    float* partial = Lpart + (size_t)SPLITS * Hh * Nn;     // 192*512
    // Opart (SPLITS*Hh*Nn*64 = 3145728 floats) aliases Q,K,V + head of rel:
    // all dead by flash4 time (flash reads only packs/eid/delta8/koddT).
    float* Opart = ws;

    qkv_gemm_k<<<dim3(Dd / 64, Nn / 64, 3), 256, 0, stream>>>(feat, Wq, bq, Wk, bk, Wv, bv, Q, K, V);
    init_rel_k<<<(int)((NN_ + 255) / 256), 256, 0, stream>>>(rel, eid);
    norm_idx_k<<<(2 * E + 255) / 256, 256, 0, stream>>>(rawidx, idxn, 2 * E);
    scatter_k<<<(E + 255) / 256, 256, 0, stream>>>(idxn, attr, rel, eid, E);
    oddsum_k<<<(2 * Nn * Hh + 255) / 256, 256, 0, stream>>>(Q, K, qodd, kodd, koddT);
    delta_k<<<(E * Hh + 255) / 256, 256, 0, stream>>>(idxn, rel, Q, K, qodd, kodd, delta8, E);
    pack_k<<<dim3(384, 3), 256, 0, stream>>>(Q, K, V, pQh, pQl, pKh, pKl, pVh, pVl);
    flash4_k<<<dim3(96, 8, SPLITS), 64, 0, stream>>>(pQh, pQl, pKh, pKl, pVh, pVl,
                                                     eid, delta8, koddT, Opart, Mpart, Lpart);
    combine_mp_k<<<96, 256, 0, stream>>>(Opart, Mpart, Lpart, partial);
    mp2_k<<<1, 128, 0, stream>>>(partial, outp);
}

// Round 5
// 219.078 us; speedup vs baseline: 3.1573x; 1.2321x over previous
//
#include <hip/hip_runtime.h>
#include <cmath>

// ---------------------------------------------------------------------------
// DistanceAwareMultiheadAttention  (N=1536, E=49152, D=512, H=8, DH=64)
//
// Round 5: QKV projection -> MFMA (was 77us f32 VALU GEMM, VALUBusy 30%).
//  - pack_fw_k: fused f32->split-bf16 convert + MFMA-fragment pack of feat/W
//  - qkvm_k: LDS-free 4-term split-bf16 MFMA GEMM (error ~2^-16, tighter
//    than the 3-term flash path that has held absmax=0.0 for 3 rounds)
//  - everything else unchanged from round 4 (passed, absmax 0.0)
// ---------------------------------------------------------------------------

constexpr int Nn  = 1536;
constexpr int Dd  = 512;
constexpr int Hh  = 8;
constexpr int DHd = 64;
constexpr int SPLITS = 4;
constexpr float SCALE_F = 362.03867196751236f;   // 256*sqrt(2)

typedef float f4 __attribute__((ext_vector_type(4)));
typedef __attribute__((ext_vector_type(4))) float f32x4;
typedef __attribute__((ext_vector_type(8))) short bf16x8;

__device__ inline unsigned short bf16_rne(float x) {
    unsigned u = __float_as_uint(x);
    unsigned r = u + 0x7fff + ((u >> 16) & 1);
    return (unsigned short)(r >> 16);
}
__device__ inline float bf16_tof(unsigned short h) {
    return __uint_as_float(((unsigned)h) << 16);
}

// ------------- pack feat / W into MFMA fragment order (hi/lo bf16) ----------
// A/B frag (16x16x32): lane L holds row m=L&15, k=(L>>4)*8+j.
// feat: pFh[tg*8+j] with tg=(mt*16+kc)*64+L  <- feat[mt*16+(L&15)][kc*32+(L>>4)*8+j]
// W:    pWh[tg*8+j] with tg=((z*32+nt)*16+kc)*64+L <- W_z[nt*16+(L&15)][kc*32+...]
__global__ __launch_bounds__(256) void pack_fw_k(
    const float* __restrict__ feat,
    const float* __restrict__ Wq, const float* __restrict__ Wk, const float* __restrict__ Wv,
    unsigned short* __restrict__ pFh, unsigned short* __restrict__ pFl,
    unsigned short* __restrict__ pWh, unsigned short* __restrict__ pWl)
{
    int tg = blockIdx.x * 256 + threadIdx.x;   // 98304 per type
    int type = blockIdx.y;                     // 0 = feat, 1 = W(all 3)
    int L = tg & 63;
    int kc = (tg >> 6) & 15;
    int t10 = tg >> 10;                        // 0..95
    const float* src;
    unsigned short *oh, *ol;
    int row, col;
    if (type == 0) {
        src = feat; oh = pFh; ol = pFl;
        row = t10 * 16 + (L & 15);
        col = kc * 32 + (L >> 4) * 8;
    } else {
        int z = t10 >> 5, nt = t10 & 31;
        src = (z == 0) ? Wq : (z == 1) ? Wk : Wv;
        oh = pWh; ol = pWl;
        row = nt * 16 + (L & 15);
        col = kc * 32 + (L >> 4) * 8;
    }
    f4 a = *(const f4*)(src + (size_t)row * Dd + col);
    f4 b = *(const f4*)(src + (size_t)row * Dd + col + 4);
    float x[8];
    #pragma unroll
    for (int j = 0; j < 4; ++j) { x[j] = a[j]; x[4 + j] = b[j]; }
    unsigned short hs[8], ls[8];
    #pragma unroll
    for (int j = 0; j < 8; ++j) {
        hs[j] = bf16_rne(x[j]);
        ls[j] = bf16_rne(x[j] - bf16_tof(hs[j]));
    }
    *(bf16x8*)(oh + (size_t)tg * 8) = *(bf16x8*)hs;
    *(bf16x8*)(ol + (size_t)tg * 8) = *(bf16x8*)ls;
}

// ------------------------ QKV projection, MFMA ------------------------------
// grid (8, 24, 3), block 256 = 4 waves. Wave computes 32 rows x 32 cols
// (2 m-tiles x 2 n-tiles), K=512 = 16 frag-chunks, 4-term split per product.
// C/D: col(n)=lane&15, row(m)=(lane>>4)*4+reg.
__global__ __launch_bounds__(256) void qkvm_k(
    const unsigned short* __restrict__ pFh, const unsigned short* __restrict__ pFl,
    const unsigned short* __restrict__ pWh, const unsigned short* __restrict__ pWl,
    const float* __restrict__ bq, const float* __restrict__ bk, const float* __restrict__ bv,
    float* __restrict__ Qo, float* __restrict__ Ko, float* __restrict__ Vo)
{
    const int z = blockIdx.z;
    const float* __restrict__ bias = (z == 0) ? bq : (z == 1) ? bk : bv;
    float* __restrict__ outp       = (z == 0) ? Qo : (z == 1) ? Ko : Vo;
    const int tid = threadIdx.x;
    const int L = tid & 63, wv = tid >> 6;
    const int l15 = L & 15, quad = L >> 4;
    const int mt0 = blockIdx.y * 4 + (wv & 1) * 2;
    const int nt0 = blockIdx.x * 4 + (wv >> 1) * 2;

    f32x4 acc[2][2];
    #pragma unroll
    for (int i = 0; i < 2; ++i)
        #pragma unroll
        for (int j = 0; j < 2; ++j) acc[i][j] = (f32x4){0.f, 0.f, 0.f, 0.f};

    for (int kc = 0; kc < 16; ++kc) {
        bf16x8 ah[2], al[2], bh[2], bl[2];
        #pragma unroll
        for (int i = 0; i < 2; ++i) {
            size_t ao = ((size_t)((mt0 + i) * 16 + kc)) * 512 + L * 8;
            ah[i] = *(const bf16x8*)(pFh + ao);
            al[i] = *(const bf16x8*)(pFl + ao);
            size_t bo = ((size_t)((z * 32 + nt0 + i) * 16 + kc)) * 512 + L * 8;
            bh[i] = *(const bf16x8*)(pWh + bo);
            bl[i] = *(const bf16x8*)(pWl + bo);
        }
        #pragma unroll
        for (int i = 0; i < 2; ++i)
            #pragma unroll
            for (int j = 0; j < 2; ++j) {
                f32x4 a = acc[i][j];
                a = __builtin_amdgcn_mfma_f32_16x16x32_bf16(ah[i], bh[j], a, 0, 0, 0);
                a = __builtin_amdgcn_mfma_f32_16x16x32_bf16(ah[i], bl[j], a, 0, 0, 0);
                a = __builtin_amdgcn_mfma_f32_16x16x32_bf16(al[i], bh[j], a, 0, 0, 0);
                a = __builtin_amdgcn_mfma_f32_16x16x32_bf16(al[i], bl[j], a, 0, 0, 0);
                acc[i][j] = a;
            }
    }

    #pragma unroll
    for (int i = 0; i < 2; ++i) {
        int row0 = (mt0 + i) * 16 + quad * 4;
        #pragma unroll
        for (int j = 0; j < 2; ++j) {
            int col = (nt0 + j) * 16 + l15;
            float b = bias[col];
            #pragma unroll
            for (int reg = 0; reg < 4; ++reg)
                outp[(size_t)(row0 + reg) * Dd + col] = acc[i][j][reg] + b;
        }
    }
}

// -------------------- pack Q/K/V into MFMA fragment order -------------------
__global__ __launch_bounds__(256) void pack_k(
    const float* __restrict__ Q, const float* __restrict__ K, const float* __restrict__ V,
    unsigned short* __restrict__ pQh, unsigned short* __restrict__ pQl,
    unsigned short* __restrict__ pKh, unsigned short* __restrict__ pKl,
    unsigned short* __restrict__ pVh, unsigned short* __restrict__ pVl)
{
    int tg = blockIdx.x * 256 + threadIdx.x;   // 98304 per type
    int type = blockIdx.y;
    int L = tg & 63;
    float x[8];
    unsigned short* oh;
    unsigned short* ol;
    if (type < 2) {
        const float* src = type ? K : Q;
        oh = type ? pKh : pQh;
        ol = type ? pKl : pQl;
        int kc = (tg >> 6) & 1;
        int mt = (tg >> 7) % 96;
        int h  = (tg >> 7) / 96;
        int row = mt * 16 + (L & 15);
        int col = h * 64 + kc * 32 + (L >> 4) * 8;
        f4 a = *(const f4*)(src + (size_t)row * Dd + col);
        f4 b = *(const f4*)(src + (size_t)row * Dd + col + 4);
        float sc = type ? 1.0f : 0.25f;
        #pragma unroll
        for (int j = 0; j < 4; ++j) { x[j] = a[j] * sc; x[4 + j] = b[j] * sc; }
    } else {
        oh = pVh; ol = pVl;
        int dt = (tg >> 6) & 3;
        int rc = (tg >> 8) % 48;
        int h  = (tg >> 8) / 48;
        int col  = h * 64 + dt * 16 + (L & 15);
        int row0 = rc * 32 + (L >> 4) * 8;
        #pragma unroll
        for (int j = 0; j < 8; ++j) x[j] = V[(size_t)(row0 + j) * Dd + col];
    }
    unsigned short hs[8], ls[8];
    #pragma unroll
    for (int j = 0; j < 8; ++j) {
        hs[j] = bf16_rne(x[j]);
        ls[j] = bf16_rne(x[j] - bf16_tof(hs[j]));
    }
    *(bf16x8*)(oh + (size_t)tg * 8) = *(bf16x8*)hs;
    *(bf16x8*)(ol + (size_t)tg * 8) = *(bf16x8*)ls;
}

// ------------------------- rel / eid init + scatter -------------------------
__global__ void init_rel_k(float* __restrict__ rel, int* __restrict__ eid)
{
    size_t i = (size_t)blockIdx.x * 256 + threadIdx.x;
    if (i < (size_t)Nn * Nn) { rel[i] = 0.f; eid[i] = -1; }
}

__global__ void norm_idx_k(const int* __restrict__ raw, int* __restrict__ idxn, int E2)
{
    int e = blockIdx.x * 256 + threadIdx.x;
    if (e >= E2) return;
    int acc = 0;
    #pragma unroll
    for (int i = 0; i < 16; ++i) acc |= raw[2 * i + 1];
    int v;
    if (acc == 0) v = raw[2 * e];
    else          v = raw[e];
    idxn[e] = v;
}

__global__ void scatter_k(const int* __restrict__ idxn, const float* __restrict__ attr,
                          float* __restrict__ rel, int* __restrict__ eid, int E)
{
    int e = blockIdx.x * 256 + threadIdx.x;
    if (e >= E) return;
    int s = idxn[e], t = idxn[E + e];
    size_t off = (size_t)s * Nn + t;
    atomicAdd(rel + off, attr[e] * SCALE_F);
    eid[off] = e;
}

// ------------------ odd-index sums (PE at rel==0 constants) -----------------
__global__ void oddsum_k(const float* __restrict__ Q, const float* __restrict__ K,
                         float* __restrict__ qodd, float* __restrict__ kodd,
                         float* __restrict__ koddT)
{
    int t = blockIdx.x * 256 + threadIdx.x;
    if (t >= 2 * Nn * Hh) return;
    const float* src = (t < Nn * Hh) ? Q : K;
    int i = (t < Nn * Hh) ? t : t - Nn * Hh;
    int n = i >> 3, h = i & 7;
    const float* row = src + (size_t)n * Dd + h * DHd;
    float s = 0.f;
    #pragma unroll
    for (int ii = 0; ii < 32; ++ii) s += row[2 * ii + 1];
    if (t < Nn * Hh) qodd[i] = s;
    else { kodd[i] = s; koddT[h * Nn + n] = 0.125f * s; }
}

// ------------------- per-edge, per-head logit corrections -------------------
__global__ __launch_bounds__(256) void delta_k(
    const int* __restrict__ idxn, const float* __restrict__ rel,
    const float* __restrict__ Q, const float* __restrict__ K,
    const float* __restrict__ qodd, const float* __restrict__ kodd,
    float* __restrict__ delta8, int E)
{
    int t = blockIdx.x * 256 + threadIdx.x;
    if (t >= E * Hh) return;
    int e = t >> 3, h = t & 7;
    int qi = idxn[e], ri = idxn[E + e];
    float x = rel[(size_t)qi * Nn + ri];
    const float* qrow = Q + (size_t)qi * Dd + h * DHd;
    const float* krow = K + (size_t)ri * Dd + h * DHd;
    float acc = 0.f;
    #pragma unroll
    for (int i = 0; i < 32; i += 2) {
        float d0 = expf(-0.28782313662425572f * (float)i);       // compile-time
        float d1 = expf(-0.28782313662425572f * (float)(i + 1)); // compile-time
        float s0, c0, s1, c1;
        __sincosf(x * d0, &s0, &c0);
        __sincosf(x * d1, &s1, &c1);
        f4 q4 = *(const f4*)(qrow + 2 * i);
        f4 k4 = *(const f4*)(krow + 2 * i);
        acc += (q4[0] + k4[0]) * s0 + (q4[1] + k4[1]) * c0
             + (q4[2] + k4[2]) * s1 + (q4[3] + k4[3]) * c1;
    }
    delta8[(size_t)e * Hh + h] = 0.125f * (acc - qodd[qi * Hh + h] - kodd[ri * Hh + h]);
}

// --------------------- flash attention, split-bf16 MFMA ---------------------
__global__ __launch_bounds__(64) void flash4_k(
    const unsigned short* __restrict__ pQh, const unsigned short* __restrict__ pQl,
    const unsigned short* __restrict__ pKh, const unsigned short* __restrict__ pKl,
    const unsigned short* __restrict__ pVh, const unsigned short* __restrict__ pVl,
    const int* __restrict__ eid, const float* __restrict__ delta8,
    const float* __restrict__ koddT,
    float* __restrict__ Opart, float* __restrict__ Mpart, float* __restrict__ Lpart)
{
    const int qt = blockIdx.x, h = blockIdx.y, s = blockIdx.z;
    const int L = threadIdx.x, quad = L >> 4, l15 = L & 15;
    const int q0 = qt * 16;
    __shared__ unsigned short phi[16][80];
    __shared__ unsigned short plo[16][80];

    bf16x8 qh[2], ql[2];
    #pragma unroll
    for (int kc = 0; kc < 2; ++kc) {
        size_t off = ((size_t)((h * 96 + qt) * 2 + kc)) * 512 + L * 8;
        qh[kc] = *(const bf16x8*)(pQh + off);
        ql[kc] = *(const bf16x8*)(pQl + off);
    }

    float m_[4], l_[4];
    f32x4 O[4];
    #pragma unroll
    for (int r = 0; r < 4; ++r) { m_[r] = -3.0e38f; l_[r] = 0.f; O[r] = (f32x4){0.f,0.f,0.f,0.f}; }

    const int NT = 24 / SPLITS;         // 6 r-tiles per split
    const int Tbase = s * NT;

    int   ecur[16];
    float kvcur[4], dcur[16];
    {
        const int r0 = Tbase * 64;
        #pragma unroll
        for (int nt = 0; nt < 4; ++nt) {
            kvcur[nt] = koddT[h * Nn + r0 + nt * 16 + l15];
            #pragma unroll
            for (int reg = 0; reg < 4; ++reg)
                ecur[nt * 4 + reg] = eid[(size_t)(q0 + quad * 4 + reg) * Nn + r0 + nt * 16 + l15];
        }
        #pragma unroll
        for (int i = 0; i < 16; ++i) {
            int e = ecur[i];
            float d = delta8[(size_t)(e < 0 ? 0 : e) * Hh + h];
            dcur[i] = (e >= 0) ? d : 0.f;
        }
    }

    for (int T = 0; T < NT; ++T) {
        const int r0 = (Tbase + T) * 64;
        const bool more = (T + 1 < NT);

        int   enxt[16];
        float kvnxt[4];
        if (more) {
            const int r1 = r0 + 64;
            #pragma unroll
            for (int nt = 0; nt < 4; ++nt) {
                kvnxt[nt] = koddT[h * Nn + r1 + nt * 16 + l15];
                #pragma unroll
                for (int reg = 0; reg < 4; ++reg)
                    enxt[nt * 4 + reg] = eid[(size_t)(q0 + quad * 4 + reg) * Nn + r1 + nt * 16 + l15];
            }
        }

        bf16x8 vh0[4], vh1[4], vl0[4], vl1[4];
        #pragma unroll
        for (int dt = 0; dt < 4; ++dt) {
            size_t vb = ((size_t)((h * 48 + (r0 >> 5)) * 4 + dt)) * 512 + L * 8;
            vh0[dt] = *(const bf16x8*)(pVh + vb);
            vh1[dt] = *(const bf16x8*)(pVh + vb + 2048);
            vl0[dt] = *(const bf16x8*)(pVl + vb);
            vl1[dt] = *(const bf16x8*)(pVl + vb + 2048);
        }

        f32x4 S[4];
        #pragma unroll
        for (int nt = 0; nt < 4; ++nt) {
            int rt = (r0 >> 4) + nt;
            size_t b0 = ((size_t)((h * 96 + rt) * 2 + 0)) * 512 + L * 8;
            bf16x8 kh0 = *(const bf16x8*)(pKh + b0);
            bf16x8 kh1 = *(const bf16x8*)(pKh + b0 + 512);
            bf16x8 kl0 = *(const bf16x8*)(pKl + b0);
            bf16x8 kl1 = *(const bf16x8*)(pKl + b0 + 512);
            f32x4 a = {0.f, 0.f, 0.f, 0.f};
            a = __builtin_amdgcn_mfma_f32_16x16x32_bf16(qh[0], kh0, a, 0, 0, 0);
            a = __builtin_amdgcn_mfma_f32_16x16x32_bf16(qh[1], kh1, a, 0, 0, 0);
            a = __builtin_amdgcn_mfma_f32_16x16x32_bf16(qh[0], kl0, a, 0, 0, 0);
            a = __builtin_amdgcn_mfma_f32_16x16x32_bf16(qh[1], kl1, a, 0, 0, 0);
            a = __builtin_amdgcn_mfma_f32_16x16x32_bf16(ql[0], kh0, a, 0, 0, 0);
            a = __builtin_amdgcn_mfma_f32_16x16x32_bf16(ql[1], kh1, a, 0, 0, 0);
            S[nt] = a;
        }

        float lg[4][4];
        #pragma unroll
        for (int nt = 0; nt < 4; ++nt)
            #pragma unroll
            for (int reg = 0; reg < 4; ++reg)
                lg[nt][reg] = S[nt][reg] + kvcur[nt] + dcur[nt * 4 + reg];

        float al[4];
        #pragma unroll
        for (int reg = 0; reg < 4; ++reg) {
            float mx = fmaxf(fmaxf(lg[0][reg], lg[1][reg]), fmaxf(lg[2][reg], lg[3][reg]));
            #pragma unroll
            for (int o = 1; o < 16; o <<= 1) mx = fmaxf(mx, __shfl_xor(mx, o));
            float mn = fmaxf(m_[reg], mx);
            al[reg] = __expf(m_[reg] - mn);
            float p[4], sp = 0.f;
            #pragma unroll
            for (int nt = 0; nt < 4; ++nt) { p[nt] = __expf(lg[nt][reg] - mn); sp += p[nt]; }
            #pragma unroll
            for (int o = 1; o < 16; o <<= 1) sp += __shfl_xor(sp, o);
            l_[reg] = l_[reg] * al[reg] + sp;
            m_[reg] = mn;
            #pragma unroll
            for (int nt = 0; nt < 4; ++nt) {
                unsigned short hi = bf16_rne(p[nt]);
                phi[quad * 4 + reg][nt * 16 + l15] = hi;
                plo[quad * 4 + reg][nt * 16 + l15] = bf16_rne(p[nt] - bf16_tof(hi));
            }
        }
        #pragma unroll
        for (int dt = 0; dt < 4; ++dt)
            #pragma unroll
            for (int reg = 0; reg < 4; ++reg) O[dt][reg] *= al[reg];

        bf16x8 ph[2], pl[2];
        #pragma unroll
        for (int kc2 = 0; kc2 < 2; ++kc2) {
            ph[kc2] = *(const bf16x8*)&phi[l15][kc2 * 32 + quad * 8];
            pl[kc2] = *(const bf16x8*)&plo[l15][kc2 * 32 + quad * 8];
        }

        #pragma unroll
        for (int dt = 0; dt < 4; ++dt) {
            f32x4 a = O[dt];
            a = __builtin_amdgcn_mfma_f32_16x16x32_bf16(ph[0], vh0[dt], a, 0, 0, 0);
            a = __builtin_amdgcn_mfma_f32_16x16x32_bf16(ph[1], vh1[dt], a, 0, 0, 0);
            a = __builtin_amdgcn_mfma_f32_16x16x32_bf16(ph[0], vl0[dt], a, 0, 0, 0);
            a = __builtin_amdgcn_mfma_f32_16x16x32_bf16(ph[1], vl1[dt], a, 0, 0, 0);
            a = __builtin_amdgcn_mfma_f32_16x16x32_bf16(pl[0], vh0[dt], a, 0, 0, 0);
            a = __builtin_amdgcn_mfma_f32_16x16x32_bf16(pl[1], vh1[dt], a, 0, 0, 0);
            O[dt] = a;
        }

        if (more) {
            #pragma unroll
            for (int i = 0; i < 16; ++i) {
                int e = enxt[i];
                float d = delta8[(size_t)(e < 0 ? 0 : e) * Hh + h];
                dcur[i] = (e >= 0) ? d : 0.f;
                ecur[i] = e;
            }
            #pragma unroll
            for (int nt = 0; nt < 4; ++nt) kvcur[nt] = kvnxt[nt];
        }
    }

    #pragma unroll
    for (int dt = 0; dt < 4; ++dt)
        #pragma unroll
        for (int reg = 0; reg < 4; ++reg)
            Opart[((size_t)(s * Hh + h) * Nn + q0 + quad * 4 + reg) * 64 + dt * 16 + l15] = O[dt][reg];
    if (l15 == 0) {
        #pragma unroll
        for (int reg = 0; reg < 4; ++reg) {
            size_t mi = (size_t)(s * Hh + h) * Nn + q0 + quad * 4 + reg;
            Mpart[mi] = m_[reg];
            Lpart[mi] = l_[reg];
        }
    }
}

// ------------------- split-K combine fused with maxpool stage 1 -------------
__global__ __launch_bounds__(256) void combine_mp_k(
    const float* __restrict__ Opart, const float* __restrict__ Mpart,
    const float* __restrict__ Lpart, float* __restrict__ partial)
{
    const int b = blockIdx.x;
    const int t = threadIdx.x;
    const int cg = (t & 127) * 4;
    const int h = cg >> 6, d = cg & 63;
    const int rh = t >> 7;
    f4 mx = {-3.0e38f, -3.0e38f, -3.0e38f, -3.0e38f};
    for (int r = 0; r < 8; ++r) {
        int q = b * 16 + rh * 8 + r;
        float m[SPLITS], ms = -3.0e38f;
        #pragma unroll
        for (int s2 = 0; s2 < SPLITS; ++s2) {
            m[s2] = Mpart[(size_t)(s2 * Hh + h) * Nn + q];
            ms = fmaxf(ms, m[s2]);
        }
        float l = 0.f;
        f4 o = {0.f, 0.f, 0.f, 0.f};
        #pragma unroll
        for (int s2 = 0; s2 < SPLITS; ++s2) {
            float w = __expf(m[s2] - ms);
            l += Lpart[(size_t)(s2 * Hh + h) * Nn + q] * w;
            f4 ov = *(const f4*)(Opart + ((size_t)(s2 * Hh + h) * Nn + q) * 64 + d);
            #pragma unroll
            for (int c = 0; c < 4; ++c) o[c] += w * ov[c];
        }
        float inv = 1.0f / l;
        #pragma unroll
        for (int c = 0; c < 4; ++c) mx[c] = fmaxf(mx[c], o[c] * inv);
    }
    *(f4*)(partial + (size_t)(b * 2 + rh) * 512 + cg) = mx;
}

__global__ __launch_bounds__(128) void mp2_k(const float* __restrict__ partial,
                                             float* __restrict__ outp)
{
    const int t = threadIdx.x;
    f4 mx = {-3.0e38f, -3.0e38f, -3.0e38f, -3.0e38f};
    for (int b = 0; b < 192; ++b) {
        f4 v = *(const f4*)(partial + (size_t)b * 512 + 4 * t);
        #pragma unroll
        for (int c = 0; c < 4; ++c) mx[c] = fmaxf(mx[c], v[c]);
    }
    *(f4*)(outp + 4 * t) = mx;
}

// ---------------------------------------------------------------------------
extern "C" void kernel_launch(void* const* d_in, const int* in_sizes, int n_in,
                              void* d_out, int out_size, void* d_ws, size_t ws_size,
                              hipStream_t stream)
{
    const float* feat   = (const float*)d_in[0];
    const int*   rawidx = (const int*)d_in[1];
    const float* attr   = (const float*)d_in[2];
    const float* Wq = (const float*)d_in[4];
    const float* bq = (const float*)d_in[5];
    const float* Wk = (const float*)d_in[6];
    const float* bk = (const float*)d_in[7];
    const float* Wv = (const float*)d_in[8];
    const float* bv = (const float*)d_in[9];
    float* outp = (float*)d_out;
    const int E = in_sizes[2];

    const size_t ND_ = (size_t)Nn * Dd;            // 786432
    const size_t NN_ = (size_t)Nn * Nn;            // 2359296
    const size_t PK_ = (size_t)Hh * 96 * 2 * 512;  // 786432 bf16 per pack array
    float* ws    = (float*)d_ws;
    float* Q     = ws;                    // 786432
    float* K     = Q + ND_;               // 786432
    float* V     = K + ND_;               // 786432
    float* rel   = V + ND_;               // 2359296
    int*   eid   = (int*)(rel + NN_);     // 2359296
    float* delta8 = (float*)(eid + NN_);  // 393216
    float* qodd  = delta8 + (size_t)E * Hh;
    float* kodd  = qodd + (size_t)Nn * Hh;
    float* koddT = kodd + (size_t)Nn * Hh;
    int*   idxn  = (int*)(koddT + (size_t)Nn * Hh);
    unsigned short* pQh = (unsigned short*)(idxn + 2 * E);
    unsigned short* pQl = pQh + PK_;
    unsigned short* pKh = pQl + PK_;
    unsigned short* pKl = pKh + PK_;
    unsigned short* pVh = pKl + PK_;
    unsigned short* pVl = pVh + PK_;
    float* Mpart = (float*)(pVl + PK_);                    // SPLITS*Hh*Nn = 49152
    float* Lpart = Mpart + (size_t)SPLITS * Hh * Nn;       // 49152
    float* partial = Lpart + (size_t)SPLITS * Hh * Nn;     // 192*512
    unsigned short* pFh = (unsigned short*)(partial + 192 * 512);  // feat/W frag packs
    unsigned short* pFl = pFh + PK_;
    unsigned short* pWh = pFl + PK_;
    unsigned short* pWl = pWh + PK_;
    // Opart (SPLITS*Hh*Nn*64 = 3145728 floats) aliases Q,K,V + head of rel:
    // all dead by flash4 time (flash reads only packs/eid/delta8/koddT).
    float* Opart = ws;

    pack_fw_k<<<dim3(384, 2), 256, 0, stream>>>(feat, Wq, Wk, Wv, pFh, pFl, pWh, pWl);
    qkvm_k<<<dim3(8, 24, 3), 256, 0, stream>>>(pFh, pFl, pWh, pWl, bq, bk, bv, Q, K, V);
    init_rel_k<<<(int)((NN_ + 255) / 256), 256, 0, stream>>>(rel, eid);
    norm_idx_k<<<(2 * E + 255) / 256, 256, 0, stream>>>(rawidx, idxn, 2 * E);
    scatter_k<<<(E + 255) / 256, 256, 0, stream>>>(idxn, attr, rel, eid, E);
    oddsum_k<<<(2 * Nn * Hh + 255) / 256, 256, 0, stream>>>(Q, K, qodd, kodd, koddT);
    delta_k<<<(E * Hh + 255) / 256, 256, 0, stream>>>(idxn, rel, Q, K, qodd, kodd, delta8, E);
    pack_k<<<dim3(384, 3), 256, 0, stream>>>(Q, K, V, pQh, pQl, pKh, pKl, pVh, pVl);
    flash4_k<<<dim3(96, 8, SPLITS), 64, 0, stream>>>(pQh, pQl, pKh, pKl, pVh, pVl,
                                                     eid, delta8, koddT, Opart, Mpart, Lpart);
    combine_mp_k<<<96, 256, 0, stream>>>(Opart, Mpart, Lpart, partial);
    mp2_k<<<1, 128, 0, stream>>>(partial, outp);
}

// Round 6
// 193.520 us; speedup vs baseline: 3.5743x; 1.1321x over previous
//
#include <hip/hip_runtime.h>
#include <cmath>

// ---------------------------------------------------------------------------
// DistanceAwareMultiheadAttention  (N=1536, E=49152, D=512, H=8, DH=64)
//
// Round 6:
//  - flash5_k: NO per-tile max/sum shuffle reductions (fixed exp offset M0=8,
//    exact softmax up to scaling; bounds: |logits| <~ 16 << 88). Row-sum
//    reduced once after the K-loop. K-fragments double-buffered one r-tile
//    ahead. Split-K combine becomes plain sums (no M partials).
//  - init vectorized (i4/f4); norm_idx folded into scatter (-1 launch).
//  - qkvm / pack_fw / delta / pack unchanged from round 5 (absmax 4.9e-4).
// ---------------------------------------------------------------------------

constexpr int Nn  = 1536;
constexpr int Dd  = 512;
constexpr int Hh  = 8;
constexpr int DHd = 64;
constexpr int SPLITS = 4;
constexpr float SCALE_F = 362.03867196751236f;   // 256*sqrt(2)
constexpr float M0 = 8.0f;                       // fixed softmax exp offset

typedef float f4 __attribute__((ext_vector_type(4)));
typedef int   i4 __attribute__((ext_vector_type(4)));
typedef __attribute__((ext_vector_type(4))) float f32x4;
typedef __attribute__((ext_vector_type(8))) short bf16x8;

__device__ inline unsigned short bf16_rne(float x) {
    unsigned u = __float_as_uint(x);
    unsigned r = u + 0x7fff + ((u >> 16) & 1);
    return (unsigned short)(r >> 16);
}
__device__ inline float bf16_tof(unsigned short h) {
    return __uint_as_float(((unsigned)h) << 16);
}

// ------------- pack feat / W into MFMA fragment order (hi/lo bf16) ----------
__global__ __launch_bounds__(256) void pack_fw_k(
    const float* __restrict__ feat,
    const float* __restrict__ Wq, const float* __restrict__ Wk, const float* __restrict__ Wv,
    unsigned short* __restrict__ pFh, unsigned short* __restrict__ pFl,
    unsigned short* __restrict__ pWh, unsigned short* __restrict__ pWl)
{
    int tg = blockIdx.x * 256 + threadIdx.x;   // 98304 per type
    int type = blockIdx.y;                     // 0 = feat, 1 = W(all 3)
    int L = tg & 63;
    int kc = (tg >> 6) & 15;
    int t10 = tg >> 10;                        // 0..95
    const float* src;
    unsigned short *oh, *ol;
    int row, col;
    if (type == 0) {
        src = feat; oh = pFh; ol = pFl;
        row = t10 * 16 + (L & 15);
        col = kc * 32 + (L >> 4) * 8;
    } else {
        int z = t10 >> 5, nt = t10 & 31;
        src = (z == 0) ? Wq : (z == 1) ? Wk : Wv;
        oh = pWh; ol = pWl;
        row = nt * 16 + (L & 15);
        col = kc * 32 + (L >> 4) * 8;
    }
    f4 a = *(const f4*)(src + (size_t)row * Dd + col);
    f4 b = *(const f4*)(src + (size_t)row * Dd + col + 4);
    float x[8];
    #pragma unroll
    for (int j = 0; j < 4; ++j) { x[j] = a[j]; x[4 + j] = b[j]; }
    unsigned short hs[8], ls[8];
    #pragma unroll
    for (int j = 0; j < 8; ++j) {
        hs[j] = bf16_rne(x[j]);
        ls[j] = bf16_rne(x[j] - bf16_tof(hs[j]));
    }
    *(bf16x8*)(oh + (size_t)tg * 8) = *(bf16x8*)hs;
    *(bf16x8*)(ol + (size_t)tg * 8) = *(bf16x8*)ls;
}

// ------------------------ QKV projection, MFMA ------------------------------
__global__ __launch_bounds__(256) void qkvm_k(
    const unsigned short* __restrict__ pFh, const unsigned short* __restrict__ pFl,
    const unsigned short* __restrict__ pWh, const unsigned short* __restrict__ pWl,
    const float* __restrict__ bq, const float* __restrict__ bk, const float* __restrict__ bv,
    float* __restrict__ Qo, float* __restrict__ Ko, float* __restrict__ Vo)
{
    const int z = blockIdx.z;
    const float* __restrict__ bias = (z == 0) ? bq : (z == 1) ? bk : bv;
    float* __restrict__ outp       = (z == 0) ? Qo : (z == 1) ? Ko : Vo;
    const int tid = threadIdx.x;
    const int L = tid & 63, wv = tid >> 6;
    const int l15 = L & 15, quad = L >> 4;
    const int mt0 = blockIdx.y * 4 + (wv & 1) * 2;
    const int nt0 = blockIdx.x * 4 + (wv >> 1) * 2;

    f32x4 acc[2][2];
    #pragma unroll
    for (int i = 0; i < 2; ++i)
        #pragma unroll
        for (int j = 0; j < 2; ++j) acc[i][j] = (f32x4){0.f, 0.f, 0.f, 0.f};

    for (int kc = 0; kc < 16; ++kc) {
        bf16x8 ah[2], al[2], bh[2], bl[2];
        #pragma unroll
        for (int i = 0; i < 2; ++i) {
            size_t ao = ((size_t)((mt0 + i) * 16 + kc)) * 512 + L * 8;
            ah[i] = *(const bf16x8*)(pFh + ao);
            al[i] = *(const bf16x8*)(pFl + ao);
            size_t bo = ((size_t)((z * 32 + nt0 + i) * 16 + kc)) * 512 + L * 8;
            bh[i] = *(const bf16x8*)(pWh + bo);
            bl[i] = *(const bf16x8*)(pWl + bo);
        }
        #pragma unroll
        for (int i = 0; i < 2; ++i)
            #pragma unroll
            for (int j = 0; j < 2; ++j) {
                f32x4 a = acc[i][j];
                a = __builtin_amdgcn_mfma_f32_16x16x32_bf16(ah[i], bh[j], a, 0, 0, 0);
                a = __builtin_amdgcn_mfma_f32_16x16x32_bf16(ah[i], bl[j], a, 0, 0, 0);
                a = __builtin_amdgcn_mfma_f32_16x16x32_bf16(al[i], bh[j], a, 0, 0, 0);
                a = __builtin_amdgcn_mfma_f32_16x16x32_bf16(al[i], bl[j], a, 0, 0, 0);
                acc[i][j] = a;
            }
    }

    #pragma unroll
    for (int i = 0; i < 2; ++i) {
        int row0 = (mt0 + i) * 16 + quad * 4;
        #pragma unroll
        for (int j = 0; j < 2; ++j) {
            int col = (nt0 + j) * 16 + l15;
            float b = bias[col];
            #pragma unroll
            for (int reg = 0; reg < 4; ++reg)
                outp[(size_t)(row0 + reg) * Dd + col] = acc[i][j][reg] + b;
        }
    }
}

// -------------------- pack Q/K/V into MFMA fragment order -------------------
__global__ __launch_bounds__(256) void pack_k(
    const float* __restrict__ Q, const float* __restrict__ K, const float* __restrict__ V,
    unsigned short* __restrict__ pQh, unsigned short* __restrict__ pQl,
    unsigned short* __restrict__ pKh, unsigned short* __restrict__ pKl,
    unsigned short* __restrict__ pVh, unsigned short* __restrict__ pVl)
{
    int tg = blockIdx.x * 256 + threadIdx.x;   // 98304 per type
    int type = blockIdx.y;
    int L = tg & 63;
    float x[8];
    unsigned short* oh;
    unsigned short* ol;
    if (type < 2) {
        const float* src = type ? K : Q;
        oh = type ? pKh : pQh;
        ol = type ? pKl : pQl;
        int kc = (tg >> 6) & 1;
        int mt = (tg >> 7) % 96;
        int h  = (tg >> 7) / 96;
        int row = mt * 16 + (L & 15);
        int col = h * 64 + kc * 32 + (L >> 4) * 8;
        f4 a = *(const f4*)(src + (size_t)row * Dd + col);
        f4 b = *(const f4*)(src + (size_t)row * Dd + col + 4);
        float sc = type ? 1.0f : 0.25f;
        #pragma unroll
        for (int j = 0; j < 4; ++j) { x[j] = a[j] * sc; x[4 + j] = b[j] * sc; }
    } else {
        oh = pVh; ol = pVl;
        int dt = (tg >> 6) & 3;
        int rc = (tg >> 8) % 48;
        int h  = (tg >> 8) / 48;
        int col  = h * 64 + dt * 16 + (L & 15);
        int row0 = rc * 32 + (L >> 4) * 8;
        #pragma unroll
        for (int j = 0; j < 8; ++j) x[j] = V[(size_t)(row0 + j) * Dd + col];
    }
    unsigned short hs[8], ls[8];
    #pragma unroll
    for (int j = 0; j < 8; ++j) {
        hs[j] = bf16_rne(x[j]);
        ls[j] = bf16_rne(x[j] - bf16_tof(hs[j]));
    }
    *(bf16x8*)(oh + (size_t)tg * 8) = *(bf16x8*)hs;
    *(bf16x8*)(ol + (size_t)tg * 8) = *(bf16x8*)ls;
}

// ------------------------- rel / eid init (vectorized) ----------------------
__global__ __launch_bounds__(256) void init_rel_k(float* __restrict__ rel, int* __restrict__ eid)
{
    size_t i = ((size_t)blockIdx.x * 256 + threadIdx.x) * 4;
    if (i < (size_t)Nn * Nn) {
        *(f4*)(rel + i) = (f4){0.f, 0.f, 0.f, 0.f};
        *(i4*)(eid + i) = (i4){-1, -1, -1, -1};
    }
}

// ----------------- scatter (with inline int64/int32 detect) -----------------
__global__ __launch_bounds__(256) void scatter_k(
    const int* __restrict__ raw, const float* __restrict__ attr,
    float* __restrict__ rel, int* __restrict__ eid, int* __restrict__ idxn, int E)
{
    int e = blockIdx.x * 256 + threadIdx.x;
    if (e >= E) return;
    int acc = 0;
    #pragma unroll
    for (int i = 0; i < 16; ++i) acc |= raw[2 * i + 1];
    int s, t;
    if (acc == 0) { s = raw[2 * e]; t = raw[2 * (E + e)]; }   // int64 low words
    else          { s = raw[e];     t = raw[E + e]; }          // plain int32
    idxn[e] = s; idxn[E + e] = t;
    size_t off = (size_t)s * Nn + t;
    atomicAdd(rel + off, attr[e] * SCALE_F);
    eid[off] = e;
}

// ------------------ odd-index sums (PE at rel==0 constants) -----------------
__global__ void oddsum_k(const float* __restrict__ Q, const float* __restrict__ K,
                         float* __restrict__ qodd, float* __restrict__ kodd,
                         float* __restrict__ koddT)
{
    int t = blockIdx.x * 256 + threadIdx.x;
    if (t >= 2 * Nn * Hh) return;
    const float* src = (t < Nn * Hh) ? Q : K;
    int i = (t < Nn * Hh) ? t : t - Nn * Hh;
    int n = i >> 3, h = i & 7;
    const float* row = src + (size_t)n * Dd + h * DHd;
    float s = 0.f;
    #pragma unroll
    for (int ii = 0; ii < 32; ++ii) s += row[2 * ii + 1];
    if (t < Nn * Hh) qodd[i] = s;
    else { kodd[i] = s; koddT[h * Nn + n] = 0.125f * s; }
}

// ------------------- per-edge, per-head logit corrections -------------------
__global__ __launch_bounds__(256) void delta_k(
    const int* __restrict__ idxn, const float* __restrict__ rel,
    const float* __restrict__ Q, const float* __restrict__ K,
    const float* __restrict__ qodd, const float* __restrict__ kodd,
    float* __restrict__ delta8, int E)
{
    int t = blockIdx.x * 256 + threadIdx.x;
    if (t >= E * Hh) return;
    int e = t >> 3, h = t & 7;
    int qi = idxn[e], ri = idxn[E + e];
    float x = rel[(size_t)qi * Nn + ri];
    const float* qrow = Q + (size_t)qi * Dd + h * DHd;
    const float* krow = K + (size_t)ri * Dd + h * DHd;
    float acc = 0.f;
    #pragma unroll
    for (int i = 0; i < 32; i += 2) {
        float d0 = expf(-0.28782313662425572f * (float)i);       // compile-time
        float d1 = expf(-0.28782313662425572f * (float)(i + 1)); // compile-time
        float s0, c0, s1, c1;
        __sincosf(x * d0, &s0, &c0);
        __sincosf(x * d1, &s1, &c1);
        f4 q4 = *(const f4*)(qrow + 2 * i);
        f4 k4 = *(const f4*)(krow + 2 * i);
        acc += (q4[0] + k4[0]) * s0 + (q4[1] + k4[1]) * c0
             + (q4[2] + k4[2]) * s1 + (q4[3] + k4[3]) * c1;
    }
    delta8[(size_t)e * Hh + h] = 0.125f * (acc - qodd[qi * Hh + h] - kodd[ri * Hh + h]);
}

// ---------------- flash attention, no-max softmax + K dbuf ------------------
// exp(logit - M0) with fixed M0: exact softmax up to a row-consistent scale
// (|logits| <~ 16, f32 exp safe to 88). No per-tile cross-lane reductions;
// row-sum reduced once after the loop. K frags double-buffered one tile ahead.
__global__ __launch_bounds__(64, 3) void flash5_k(
    const unsigned short* __restrict__ pQh, const unsigned short* __restrict__ pQl,
    const unsigned short* __restrict__ pKh, const unsigned short* __restrict__ pKl,
    const unsigned short* __restrict__ pVh, const unsigned short* __restrict__ pVl,
    const int* __restrict__ eid, const float* __restrict__ delta8,
    const float* __restrict__ koddT,
    float* __restrict__ Opart, float* __restrict__ Lpart)
{
    const int qt = blockIdx.x, h = blockIdx.y, s = blockIdx.z;
    const int L = threadIdx.x, quad = L >> 4, l15 = L & 15;
    const int q0 = qt * 16;
    __shared__ unsigned short phi[16][80];
    __shared__ unsigned short plo[16][80];

    bf16x8 qh[2], ql[2];
    #pragma unroll
    for (int kc = 0; kc < 2; ++kc) {
        size_t off = ((size_t)((h * 96 + qt) * 2 + kc)) * 512 + L * 8;
        qh[kc] = *(const bf16x8*)(pQh + off);
        ql[kc] = *(const bf16x8*)(pQl + off);
    }

    f32x4 O[4];
    float lsum[4];
    #pragma unroll
    for (int r = 0; r < 4; ++r) { lsum[r] = 0.f; O[r] = (f32x4){0.f, 0.f, 0.f, 0.f}; }

    const int NT = 24 / SPLITS;         // 6 r-tiles per split
    const int Tbase = s * NT;

    // ---- K frag double buffer: preload tile 0 ----
    bf16x8 kh0[4], kh1[4], kl0[4], kl1[4];
    {
        const int r0 = Tbase * 64;
        #pragma unroll
        for (int nt = 0; nt < 4; ++nt) {
            size_t b0 = ((size_t)((h * 96 + (r0 >> 4) + nt) * 2)) * 512 + L * 8;
            kh0[nt] = *(const bf16x8*)(pKh + b0);
            kh1[nt] = *(const bf16x8*)(pKh + b0 + 512);
            kl0[nt] = *(const bf16x8*)(pKl + b0);
            kl1[nt] = *(const bf16x8*)(pKl + b0 + 512);
        }
    }

    // ---- meta for tile 0 ----
    float kvcur[4], dcur[16];
    {
        const int r0 = Tbase * 64;
        int ecur[16];
        #pragma unroll
        for (int nt = 0; nt < 4; ++nt) {
            kvcur[nt] = koddT[h * Nn + r0 + nt * 16 + l15];
            #pragma unroll
            for (int reg = 0; reg < 4; ++reg)
                ecur[nt * 4 + reg] = eid[(size_t)(q0 + quad * 4 + reg) * Nn + r0 + nt * 16 + l15];
        }
        #pragma unroll
        for (int i = 0; i < 16; ++i) {
            int e = ecur[i];
            float d = delta8[(size_t)(e < 0 ? 0 : e) * Hh + h];
            dcur[i] = (e >= 0) ? d : 0.f;
        }
    }

    for (int T = 0; T < NT; ++T) {
        const int r0 = (Tbase + T) * 64;
        const bool more = (T + 1 < NT);

        // ---- prefetch next tile's eid + koddT ----
        int   enxt[16];
        float kvnxt[4];
        if (more) {
            const int r1 = r0 + 64;
            #pragma unroll
            for (int nt = 0; nt < 4; ++nt) {
                kvnxt[nt] = koddT[h * Nn + r1 + nt * 16 + l15];
                #pragma unroll
                for (int reg = 0; reg < 4; ++reg)
                    enxt[nt * 4 + reg] = eid[(size_t)(q0 + quad * 4 + reg) * Nn + r1 + nt * 16 + l15];
            }
        }

        // ---- V loads for this tile (early issue; consumed after exp) ----
        bf16x8 vh0[4], vh1[4], vl0[4], vl1[4];
        #pragma unroll
        for (int dt = 0; dt < 4; ++dt) {
            size_t vb = ((size_t)((h * 48 + (r0 >> 5)) * 4 + dt)) * 512 + L * 8;
            vh0[dt] = *(const bf16x8*)(pVh + vb);
            vh1[dt] = *(const bf16x8*)(pVh + vb + 2048);
            vl0[dt] = *(const bf16x8*)(pVl + vb);
            vl1[dt] = *(const bf16x8*)(pVl + vb + 2048);
        }

        // ---- S = 0.25 * Q K^T from the current K buffer ----
        f32x4 S[4];
        #pragma unroll
        for (int nt = 0; nt < 4; ++nt) {
            f32x4 a = {0.f, 0.f, 0.f, 0.f};
            a = __builtin_amdgcn_mfma_f32_16x16x32_bf16(qh[0], kh0[nt], a, 0, 0, 0);
            a = __builtin_amdgcn_mfma_f32_16x16x32_bf16(qh[1], kh1[nt], a, 0, 0, 0);
            a = __builtin_amdgcn_mfma_f32_16x16x32_bf16(qh[0], kl0[nt], a, 0, 0, 0);
            a = __builtin_amdgcn_mfma_f32_16x16x32_bf16(qh[1], kl1[nt], a, 0, 0, 0);
            a = __builtin_amdgcn_mfma_f32_16x16x32_bf16(ql[0], kh0[nt], a, 0, 0, 0);
            a = __builtin_amdgcn_mfma_f32_16x16x32_bf16(ql[1], kh1[nt], a, 0, 0, 0);
            S[nt] = a;
        }

        // ---- refill K buffer for next tile (long issue->use distance) ----
        if (more) {
            const int r1 = r0 + 64;
            #pragma unroll
            for (int nt = 0; nt < 4; ++nt) {
                size_t b0 = ((size_t)((h * 96 + (r1 >> 4) + nt) * 2)) * 512 + L * 8;
                kh0[nt] = *(const bf16x8*)(pKh + b0);
                kh1[nt] = *(const bf16x8*)(pKh + b0 + 512);
                kl0[nt] = *(const bf16x8*)(pKl + b0);
                kl1[nt] = *(const bf16x8*)(pKl + b0 + 512);
            }
        }

        // ---- p = exp(logit - M0); accumulate row sums; pack to LDS ----
        #pragma unroll
        for (int reg = 0; reg < 4; ++reg) {
            float p[4];
            #pragma unroll
            for (int nt = 0; nt < 4; ++nt) {
                p[nt] = __expf(S[nt][reg] + kvcur[nt] + dcur[nt * 4 + reg] - M0);
                lsum[reg] += p[nt];
                unsigned short hi = bf16_rne(p[nt]);
                phi[quad * 4 + reg][nt * 16 + l15] = hi;
                plo[quad * 4 + reg][nt * 16 + l15] = bf16_rne(p[nt] - bf16_tof(hi));
            }
        }

        // ---- P A-frags from LDS (single wave: DS in-order, no barrier) ----
        bf16x8 ph[2], pl[2];
        #pragma unroll
        for (int kc2 = 0; kc2 < 2; ++kc2) {
            ph[kc2] = *(const bf16x8*)&phi[l15][kc2 * 32 + quad * 8];
            pl[kc2] = *(const bf16x8*)&plo[l15][kc2 * 32 + quad * 8];
        }

        // ---- O += P V ----
        #pragma unroll
        for (int dt = 0; dt < 4; ++dt) {
            f32x4 a = O[dt];
            a = __builtin_amdgcn_mfma_f32_16x16x32_bf16(ph[0], vh0[dt], a, 0, 0, 0);
            a = __builtin_amdgcn_mfma_f32_16x16x32_bf16(ph[1], vh1[dt], a, 0, 0, 0);
            a = __builtin_amdgcn_mfma_f32_16x16x32_bf16(ph[0], vl0[dt], a, 0, 0, 0);
            a = __builtin_amdgcn_mfma_f32_16x16x32_bf16(ph[1], vl1[dt], a, 0, 0, 0);
            a = __builtin_amdgcn_mfma_f32_16x16x32_bf16(pl[0], vh0[dt], a, 0, 0, 0);
            a = __builtin_amdgcn_mfma_f32_16x16x32_bf16(pl[1], vh1[dt], a, 0, 0, 0);
            O[dt] = a;
        }

        // ---- gather next tile's delta (eid prefetch has landed) ----
        if (more) {
            #pragma unroll
            for (int i = 0; i < 16; ++i) {
                int e = enxt[i];
                float d = delta8[(size_t)(e < 0 ? 0 : e) * Hh + h];
                dcur[i] = (e >= 0) ? d : 0.f;
            }
            #pragma unroll
            for (int nt = 0; nt < 4; ++nt) kvcur[nt] = kvnxt[nt];
        }
    }

    // ---- one deferred row-sum reduction (within each quad's 16 lanes) ----
    #pragma unroll
    for (int reg = 0; reg < 4; ++reg) {
        #pragma unroll
        for (int o = 1; o < 16; o <<= 1) lsum[reg] += __shfl_xor(lsum[reg], o);
    }

    // ---- store partials ----
    #pragma unroll
    for (int dt = 0; dt < 4; ++dt)
        #pragma unroll
        for (int reg = 0; reg < 4; ++reg)
            Opart[((size_t)(s * Hh + h) * Nn + q0 + quad * 4 + reg) * 64 + dt * 16 + l15] = O[dt][reg];
    if (l15 == 0) {
        #pragma unroll
        for (int reg = 0; reg < 4; ++reg)
            Lpart[(size_t)(s * Hh + h) * Nn + q0 + quad * 4 + reg] = lsum[reg];
    }
}

// ------------- split-K combine (plain sums) fused with maxpool s1 -----------
__global__ __launch_bounds__(256) void combine_mp_k(
    const float* __restrict__ Opart, const float* __restrict__ Lpart,
    float* __restrict__ partial)
{
    const int b = blockIdx.x;
    const int t = threadIdx.x;
    const int cg = (t & 127) * 4;
    const int h = cg >> 6, d = cg & 63;
    const int rh = t >> 7;
    f4 mx = {-3.0e38f, -3.0e38f, -3.0e38f, -3.0e38f};
    for (int r = 0; r < 8; ++r) {
        int q = b * 16 + rh * 8 + r;
        float l = 0.f;
        f4 o = {0.f, 0.f, 0.f, 0.f};
        #pragma unroll
        for (int s2 = 0; s2 < SPLITS; ++s2) {
            l += Lpart[(size_t)(s2 * Hh + h) * Nn + q];
            f4 ov = *(const f4*)(Opart + ((size_t)(s2 * Hh + h) * Nn + q) * 64 + d);
            #pragma unroll
            for (int c = 0; c < 4; ++c) o[c] += ov[c];
        }
        float inv = 1.0f / l;
        #pragma unroll
        for (int c = 0; c < 4; ++c) mx[c] = fmaxf(mx[c], o[c] * inv);
    }
    *(f4*)(partial + (size_t)(b * 2 + rh) * 512 + cg) = mx;
}

__global__ __launch_bounds__(128) void mp2_k(const float* __restrict__ partial,
                                             float* __restrict__ outp)
{
    const int t = threadIdx.x;
    f4 mx = {-3.0e38f, -3.0e38f, -3.0e38f, -3.0e38f};
    for (int b = 0; b < 192; ++b) {
        f4 v = *(const f4*)(partial + (size_t)b * 512 + 4 * t);
        #pragma unroll
        for (int c = 0; c < 4; ++c) mx[c] = fmaxf(mx[c], v[c]);
    }
    *(f4*)(outp + 4 * t) = mx;
}

// ---------------------------------------------------------------------------
extern "C" void kernel_launch(void* const* d_in, const int* in_sizes, int n_in,
                              void* d_out, int out_size, void* d_ws, size_t ws_size,
                              hipStream_t stream)
{
    const float* feat   = (const float*)d_in[0];
    const int*   rawidx = (const int*)d_in[1];
    const float* attr   = (const float*)d_in[2];
    const float* Wq = (const float*)d_in[4];
    const float* bq = (const float*)d_in[5];
    const float* Wk = (const float*)d_in[6];
    const float* bk = (const float*)d_in[7];
    const float* Wv = (const float*)d_in[8];
    const float* bv = (const float*)d_in[9];
    float* outp = (float*)d_out;
    const int E = in_sizes[2];

    const size_t ND_ = (size_t)Nn * Dd;            // 786432
    const size_t NN_ = (size_t)Nn * Nn;            // 2359296
    const size_t PK_ = (size_t)Hh * 96 * 2 * 512;  // 786432 bf16 per pack array
    float* ws    = (float*)d_ws;
    float* Q     = ws;                    // 786432
    float* K     = Q + ND_;               // 786432
    float* V     = K + ND_;               // 786432
    float* rel   = V + ND_;               // 2359296
    int*   eid   = (int*)(rel + NN_);     // 2359296
    float* delta8 = (float*)(eid + NN_);  // 393216
    float* qodd  = delta8 + (size_t)E * Hh;
    float* kodd  = qodd + (size_t)Nn * Hh;
    float* koddT = kodd + (size_t)Nn * Hh;
    int*   idxn  = (int*)(koddT + (size_t)Nn * Hh);
    unsigned short* pQh = (unsigned short*)(idxn + 2 * E);
    unsigned short* pQl = pQh + PK_;
    unsigned short* pKh = pQl + PK_;
    unsigned short* pKl = pKh + PK_;
    unsigned short* pVh = pKl + PK_;
    unsigned short* pVl = pVh + PK_;
    float* Lpart = (float*)(pVl + PK_);                    // SPLITS*Hh*Nn = 49152
    float* partial = Lpart + (size_t)SPLITS * Hh * Nn;     // 192*512
    unsigned short* pFh = (unsigned short*)(partial + 192 * 512);  // feat/W packs
    unsigned short* pFl = pFh + PK_;
    unsigned short* pWh = pFl + PK_;
    unsigned short* pWl = pWh + PK_;
    // Opart (SPLITS*Hh*Nn*64 = 3145728 floats) aliases Q,K,V + head of rel:
    // all dead by flash5 time (flash reads only packs/eid/delta8/koddT).
    float* Opart = ws;

    pack_fw_k<<<dim3(384, 2), 256, 0, stream>>>(feat, Wq, Wk, Wv, pFh, pFl, pWh, pWl);
    qkvm_k<<<dim3(8, 24, 3), 256, 0, stream>>>(pFh, pFl, pWh, pWl, bq, bk, bv, Q, K, V);
    init_rel_k<<<(int)((NN_ / 4 + 255) / 256), 256, 0, stream>>>(rel, eid);
    scatter_k<<<(E + 255) / 256, 256, 0, stream>>>(rawidx, attr, rel, eid, idxn, E);
    oddsum_k<<<(2 * Nn * Hh + 255) / 256, 256, 0, stream>>>(Q, K, qodd, kodd, koddT);
    delta_k<<<(E * Hh + 255) / 256, 256, 0, stream>>>(idxn, rel, Q, K, qodd, kodd, delta8, E);
    pack_k<<<dim3(384, 3), 256, 0, stream>>>(Q, K, V, pQh, pQl, pKh, pKl, pVh, pVl);
    flash5_k<<<dim3(96, 8, SPLITS), 64, 0, stream>>>(pQh, pQl, pKh, pKl, pVh, pVl,
                                                     eid, delta8, koddT, Opart, Lpart);
    combine_mp_k<<<96, 256, 0, stream>>>(Opart, Lpart, partial);
    mp2_k<<<1, 128, 0, stream>>>(partial, outp);
}